// Round 11
// baseline (3886.138 us; speedup 1.0000x reference)
//
#include <hip/hip_runtime.h>
#include <hip/hip_bf16.h>
#include <math.h>

typedef __hip_bfloat16 bf16;
typedef __attribute__((ext_vector_type(8))) short short8b;
typedef __attribute__((ext_vector_type(8))) __bf16 bf16x8;
typedef __attribute__((ext_vector_type(4))) float f32x4;
typedef __attribute__((ext_vector_type(4))) unsigned u32x4;

#define SCALE_F 0.04419417382415922f  // 1/sqrt(512)

// ---- MFMA wrapper tolerant of either builtin signature (v8i16 or v8bf16) ----
template <typename V>
static __device__ inline auto mfma_try(V a, V b, f32x4 c, int)
    -> decltype(__builtin_amdgcn_mfma_f32_16x16x32_bf16(a, b, c, 0, 0, 0)) {
  return __builtin_amdgcn_mfma_f32_16x16x32_bf16(a, b, c, 0, 0, 0);
}
template <typename V>
static __device__ inline auto mfma_try(V a, V b, f32x4 c, long)
    -> decltype(__builtin_amdgcn_mfma_f32_16x16x32_bf16(
        __builtin_bit_cast(bf16x8, a), __builtin_bit_cast(bf16x8, b), c, 0, 0, 0)) {
  return __builtin_amdgcn_mfma_f32_16x16x32_bf16(
      __builtin_bit_cast(bf16x8, a), __builtin_bit_cast(bf16x8, b), c, 0, 0, 0);
}
static __device__ inline f32x4 MFMA(short8b a, short8b b, f32x4 c) {
  return mfma_try(a, b, c, 0);
}

static __device__ inline short8b ldb8(const bf16* p) {
  return *reinterpret_cast<const short8b*>(p);
}
static __device__ inline float b2f(bf16 v) { return __bfloat162float(v); }
static __device__ inline bf16 f2b(float v) { return __float2bfloat16(v); }
static __device__ inline float s2f(short s) {
  unsigned u = ((unsigned)(unsigned short)s) << 16;
  return __builtin_bit_cast(float, u);
}
static __device__ inline unsigned pack2(float lo, float hi) {
  const unsigned a = (unsigned)__builtin_bit_cast(unsigned short, f2b(lo));
  const unsigned b = (unsigned)__builtin_bit_cast(unsigned short, f2b(hi));
  return a | (b << 16);
}
static __device__ inline float sigm(float x) { return 1.f / (1.f + expf(-x)); }

// write-through stores: bypass L1/L2, land at the LLC (device coherence
// point) -> cross-XCD visible without cache-wide fence ops. (R4-proven.)
static __device__ inline void st2_wt(bf16* p, float v) {
  unsigned ud = (unsigned)__builtin_bit_cast(unsigned short, f2b(v));
  asm volatile("global_store_short %0, %1, off sc0 sc1" ::"v"(p), "v"(ud)
               : "memory");
}
static __device__ inline void st4_wt(bf16* p, float lo, float hi) {
  unsigned ud = pack2(lo, hi);
  asm volatile("global_store_dword %0, %1, off sc0 sc1" ::"v"(p), "v"(ud)
               : "memory");
}

static __device__ inline void st_flag(unsigned* p, unsigned v) {
  asm volatile("global_store_dword %0, %1, off sc0 sc1" ::"v"(p), "v"(v)
               : "memory");
}
static __device__ inline unsigned ld_flag(const unsigned* p) {
  unsigned v;
  asm volatile("global_load_dword %0, %1, off sc0 sc1\n\ts_waitcnt vmcnt(0)"
               : "=v"(v)
               : "v"(p)
               : "memory");
  return v;
}

// batched LLC-direct load of two contiguous 64B rows (8 x dwordx4, sc0 sc1):
// addresses are REUSED across steps so reads must bypass L1/L2; single asm
// block keeps 8 loads in flight, one latency round trip.
static __device__ inline void ld_up_rows(const bf16* p0, const bf16* p1,
                                         u32x4& q0, u32x4& q1, u32x4& q2, u32x4& q3,
                                         u32x4& q4, u32x4& q5, u32x4& q6, u32x4& q7) {
  asm volatile(
      "global_load_dwordx4 %0, %8, off sc0 sc1\n\t"
      "global_load_dwordx4 %1, %8, off offset:16 sc0 sc1\n\t"
      "global_load_dwordx4 %2, %8, off offset:32 sc0 sc1\n\t"
      "global_load_dwordx4 %3, %8, off offset:48 sc0 sc1\n\t"
      "global_load_dwordx4 %4, %9, off sc0 sc1\n\t"
      "global_load_dwordx4 %5, %9, off offset:16 sc0 sc1\n\t"
      "global_load_dwordx4 %6, %9, off offset:32 sc0 sc1\n\t"
      "global_load_dwordx4 %7, %9, off offset:48 sc0 sc1\n\t"
      "s_waitcnt vmcnt(0)"
      : "=&v"(q0), "=&v"(q1), "=&v"(q2), "=&v"(q3),
        "=&v"(q4), "=&v"(q5), "=&v"(q6), "=&v"(q7)
      : "v"(p0), "v"(p1)
      : "memory");
}

// ---- per-direction 32-wide LLC flag barrier (R4-proven protocol) ----
static __device__ inline void gbar32(unsigned* flg, unsigned ep, int g, int tid) {
  asm volatile("s_waitcnt vmcnt(0)" ::: "memory");
  __syncthreads();
  if (tid < 64) {
    unsigned* row = flg + (size_t)ep * 64;
    if (tid == 0) st_flag(row + g, 1u);
    while (true) {
      const unsigned v = ld_flag(row + (tid & 31));
      if (__ballot(v != 0) == ~0ull) break;
      __builtin_amdgcn_s_sleep(1);
    }
  }
  __syncthreads();
}

// =======================  generic MFMA GEMM (prep)  =======================
template <typename OutT, bool HAS_BIAS>
__global__ __launch_bounds__(256) void gemm_k(
    const bf16* __restrict__ A, const bf16* __restrict__ Bw,
    OutT* __restrict__ C, const float* __restrict__ bias,
    int M, int N, int K) {
  const int lane = threadIdx.x & 63;
  const int wid = threadIdx.x >> 6;
  const int m0 = blockIdx.y * 128 + (wid >> 1) * 64;
  const int n0 = blockIdx.x * 128 + (wid & 1) * 64;
  const int lr = lane & 15;
  const int lk = (lane >> 4) * 8;
  f32x4 acc[4][4];
#pragma unroll
  for (int i = 0; i < 4; ++i)
#pragma unroll
    for (int j = 0; j < 4; ++j) acc[i][j] = (f32x4){0.f, 0.f, 0.f, 0.f};
  const bf16* Ap = A + (size_t)(m0 + lr) * K + lk;
  const bf16* Bp = Bw + (size_t)(n0 + lr) * K + lk;
  for (int k0 = 0; k0 < K; k0 += 32) {
    short8b av[4], bv[4];
#pragma unroll
    for (int i = 0; i < 4; ++i) av[i] = ldb8(Ap + (size_t)i * 16 * K + k0);
#pragma unroll
    for (int i = 0; i < 4; ++i) bv[i] = ldb8(Bp + (size_t)i * 16 * K + k0);
#pragma unroll
    for (int mi = 0; mi < 4; ++mi)
#pragma unroll
      for (int ni = 0; ni < 4; ++ni)
        acc[mi][ni] = MFMA(av[mi], bv[ni], acc[mi][ni]);
  }
  const int rb = (lane >> 4) * 4;
#pragma unroll
  for (int mi = 0; mi < 4; ++mi) {
#pragma unroll
    for (int r = 0; r < 4; ++r) {
      const int row = m0 + mi * 16 + rb + r;
#pragma unroll
      for (int ni = 0; ni < 4; ++ni) {
        const int col = n0 + ni * 16 + lr;
        float v = acc[mi][ni][r];
        if (HAS_BIAS) v += bias[col];
        if constexpr (sizeof(OutT) == 2) {
          C[(size_t)row * N + col] = f2b(v);
        } else {
          C[(size_t)row * N + col] = v;
        }
      }
    }
  }
}

// Output GEMM M=2048 N=32000 K=1024, LDS-staged (128x128 tile, BK=32,
// reg-staged global->LDS, 2 barriers/K-step, ds_read_b128 frags).
__global__ __launch_bounds__(256) void gemm_out(
    const bf16* __restrict__ A, const bf16* __restrict__ Bw,
    float* __restrict__ C, const float* __restrict__ bias) {
  constexpr int K = 1024, N = 32000;
  __shared__ bf16 As[128 * 32];
  __shared__ bf16 Bs[128 * 32];
  const int wgid = blockIdx.x;            // 4000 = 16 m x 250 n, m fastest
  const int mt = wgid & 15, nt = wgid >> 4;
  const int tid = threadIdx.x, lane = tid & 63, wv = tid >> 6;
  const int m0 = mt * 128, n0 = nt * 128;
  const int lr16 = lane & 15, kb = lane >> 4, koff = kb * 8;
  // staging: chunk c in [0,512): row=c>>2, quarter=c&3; thread owns c=tid, tid+256
  const int r0 = tid >> 2, q0 = tid & 3;
  const int r1 = (tid + 256) >> 2;
  const bf16* Ap0 = A + (size_t)(m0 + r0) * K + q0 * 8;
  const bf16* Ap1 = A + (size_t)(m0 + r1) * K + q0 * 8;
  const bf16* Bp0 = Bw + (size_t)(n0 + r0) * K + q0 * 8;
  const bf16* Bp1 = Bw + (size_t)(n0 + r1) * K + q0 * 8;
  const int wm = (wv >> 1) * 64, wn = (wv & 1) * 64;
  f32x4 acc[4][4];
#pragma unroll
  for (int i = 0; i < 4; ++i)
#pragma unroll
    for (int j = 0; j < 4; ++j) acc[i][j] = (f32x4){0.f, 0.f, 0.f, 0.f};
  short8b a0 = ldb8(Ap0), a1 = ldb8(Ap1), b0 = ldb8(Bp0), b1 = ldb8(Bp1);
  for (int k0 = 0; k0 < K; k0 += 32) {
    __syncthreads();                       // previous compute done, LDS free
    *reinterpret_cast<short8b*>(&As[tid * 8]) = a0;
    *reinterpret_cast<short8b*>(&As[(tid + 256) * 8]) = a1;
    *reinterpret_cast<short8b*>(&Bs[tid * 8]) = b0;
    *reinterpret_cast<short8b*>(&Bs[(tid + 256) * 8]) = b1;
    __syncthreads();
    if (k0 + 32 < K) {                     // prefetch next tile into regs
      a0 = ldb8(Ap0 + k0 + 32);
      a1 = ldb8(Ap1 + k0 + 32);
      b0 = ldb8(Bp0 + k0 + 32);
      b1 = ldb8(Bp1 + k0 + 32);
    }
    short8b af[4], bfr[4];
#pragma unroll
    for (int i = 0; i < 4; ++i) {
      af[i] = *reinterpret_cast<const short8b*>(&As[(wm + i * 16 + lr16) * 32 + koff]);
      bfr[i] = *reinterpret_cast<const short8b*>(&Bs[(wn + i * 16 + lr16) * 32 + koff]);
    }
#pragma unroll
    for (int mi = 0; mi < 4; ++mi)
#pragma unroll
      for (int ni = 0; ni < 4; ++ni)
        acc[mi][ni] = MFMA(af[mi], bfr[ni], acc[mi][ni]);
  }
#pragma unroll
  for (int mi = 0; mi < 4; ++mi) {
#pragma unroll
    for (int r = 0; r < 4; ++r) {
      const int row = m0 + wm + mi * 16 + kb * 4 + r;
#pragma unroll
      for (int ni = 0; ni < 4; ++ni) {
        const int col = n0 + wn + ni * 16 + lr16;
        C[(size_t)row * N + col] = acc[mi][ni][r] + bias[col];
      }
    }
  }
}

// =======================  prep kernels  =======================
__global__ void k_xg(const float* __restrict__ emb, const int* __restrict__ trg,
                     bf16* __restrict__ xg) {
  const int i = blockIdx.x * 256 + threadIdx.x;   // 2048*512 exact
  const int r = i >> 9, e = i & 511;
  const int t = r >> 5, b = r & 31;
  const int tok = trg[b * 64 + t];
  xg[i] = f2b(emb[(size_t)tok * 512 + e]);
}

__global__ void k_srcb(const float* __restrict__ s, bf16* __restrict__ d) {
  const int i = blockIdx.x * 256 + threadIdx.x;   // 2048*1024 exact
  d[i] = f2b(s[i]);
}

__global__ void k_fcw(const float* __restrict__ s, bf16* __restrict__ d) {
  const size_t stride = (size_t)gridDim.x * blockDim.x;
  for (size_t i = blockIdx.x * (size_t)blockDim.x + threadIdx.x;
       i < (size_t)32000 * 1024; i += stride)
    d[i] = f2b(s[i]);
}

// Bm[b*64+s][o] -> Bmt[b][o][s]  (dense s-contiguous rows for the a2 dot)
__global__ void k_bmt(const bf16* __restrict__ in, bf16* __restrict__ out) {
  const int i = blockIdx.x * 256 + threadIdx.x;   // 32*512*64 = 1048576 exact
  const int b = i >> 15, rem = i & 32767, o = rem >> 6, s = rem & 63;
  out[i] = in[(size_t)(b * 64 + s) * 512 + o];
}

__global__ void k_wpack(const float* __restrict__ fWih, const float* __restrict__ fWhh,
                        const float* __restrict__ bWih, const float* __restrict__ bWhh,
                        const float* __restrict__ fattW, const float* __restrict__ battW,
                        const float* __restrict__ bahW, const float* __restrict__ fahW,
                        bf16* Wxf, bf16* Wxb, bf16* Wrecf, bf16* Wrecb,
                        bf16* attWtf, bf16* attWtb, bf16* ahW2f, bf16* ahW2b,
                        bf16* Wh1f, bf16* Wh1b) {
  const int stride = gridDim.x * blockDim.x;
  const int i0 = blockIdx.x * blockDim.x + threadIdx.x;
  for (int i = i0; i < 2048 * 512; i += stride) {        // Wih x-slice
    const int gc = i >> 9, k = i & 511;
    Wxf[i] = f2b(fWih[(size_t)gc * 1024 + k]);
    Wxb[i] = f2b(bWih[(size_t)gc * 1024 + k]);
  }
  for (int i = i0; i < 2048 * 1024; i += stride) {       // [Wih_h | Whh]
    const int gc = i >> 10, k = i & 1023;
    float vf, vb;
    if (k < 512) { vf = fWih[(size_t)gc * 1024 + 512 + k]; vb = bWih[(size_t)gc * 1024 + 512 + k]; }
    else         { vf = fWhh[(size_t)gc * 512 + k - 512]; vb = bWhh[(size_t)gc * 512 + k - 512]; }
    Wrecf[i] = f2b(vf); Wrecb[i] = f2b(vb);
  }
  for (int i = i0; i < 512 * 1024; i += stride) {        // attW transpose
    const int j = i >> 10, d = i & 1023;
    attWtf[i] = f2b(fattW[(size_t)d * 512 + j]);
    attWtb[i] = f2b(battW[(size_t)d * 512 + j]);
  }
  for (int i = i0; i < 512 * 1024; i += stride) {        // ah_W ct-slice (swapped: fwd uses bah)
    const int o = i >> 10, d = i & 1023;
    ahW2f[i] = f2b(bahW[(size_t)o * 1536 + 512 + d]);
    ahW2b[i] = f2b(fahW[(size_t)o * 1536 + 512 + d]);
  }
  for (int i = i0; i < 512 * 512; i += stride) {         // ah_W h-slice bf16 [o][k]
    const int o = i >> 9, k = i & 511;
    Wh1f[i] = f2b(bahW[(size_t)o * 1536 + k]);
    Wh1b[i] = f2b(fahW[(size_t)o * 1536 + k]);
  }
}

__global__ void k_c0(const float* __restrict__ src, const float* __restrict__ fb,
                     const float* __restrict__ bb, float* __restrict__ c0f,
                     float* __restrict__ c0b) {
  const int r = blockIdx.x;
  const int tid = threadIdx.x;
  float pf = 0.f, pb = 0.f;
  for (int d = tid; d < 1024; d += 256) {
    const float s = src[(size_t)r * 1024 + d];
    pf += s * fb[d];
    pb += s * bb[d];
  }
#pragma unroll
  for (int d = 1; d < 64; d <<= 1) { pf += __shfl_xor(pf, d); pb += __shfl_xor(pb, d); }
  __shared__ float rf[4], rb2[4];
  if ((tid & 63) == 0) { rf[tid >> 6] = pf; rb2[tid >> 6] = pb; }
  __syncthreads();
  if (tid == 0) {
    c0f[r] = (rf[0] + rf[1] + rf[2] + rf[3]) * SCALE_F;
    c0b[r] = (rb2[0] + rb2[1] + rb2[2] + rb2[3]) * SCALE_F;
  }
}

// rolling state buffers per dir: hh[65][32][512], hb[65][32][512] bf16
__global__ void k_init(const float* __restrict__ feed, const float* __restrict__ hid,
                       bf16* hh0, bf16* hh1, bf16* hb0, bf16* hb1,
                       float* cst0, float* cst1) {
  const int i = blockIdx.x * 256 + threadIdx.x;   // 32*512 exact
  const int b = i >> 9, k = i & 511;
  hh0[i] = f2b(feed[k]);
  hh1[i] = f2b(feed[512 + k]);
  hb0[i] = f2b(hid[k]);
  hb1[i] = f2b(hid[1024 + k]);
  cst0[k * 32 + b] = hid[512 + k];
  cst1[k * 32 + b] = hid[1536 + k];
}

// =======================  sequential scan (2 barriers/step)  ==================
// Phase A (block g = j-slice): gates MFMA + cell + h WT + U-PARTIALS via MFMA
//   Up[b][o][g] = Wh1[o, jslice g] . h[b, jslice g]  (bf16, WT)
// Phase B (block g = batch): attention + softmax + a2 + U-sum + hhat.
struct ScanP {
  const bf16* Wrec[2]; const bf16* Xp[2]; const bf16* Af[2]; const bf16* Bmt[2];
  const bf16* Wh1[2]; const float* bih[2]; const float* bhh[2];
  const float* c0[2]; const float* ahb[2]; const float* mask;
  bf16* hh[2]; bf16* hb[2]; bf16* Up[2]; float* cst[2]; bf16* hcat; unsigned* flags;
};

__global__ __launch_bounds__(256) void scan_k(ScanP P) {
  const int blk = blockIdx.x;     // 64 blocks
  const int dir = blk >> 5;       // 0 fwd, 1 bwd
  const int g = blk & 31;         // PhaseA: j-slice; PhaseB: batch index
  const int tid = threadIdx.x;
  const int lane = tid & 63;
  const int wv = tid >> 6;

  const bf16* __restrict__ Wrec = P.Wrec[dir];
  const bf16* __restrict__ Xp = P.Xp[dir];
  const bf16* __restrict__ Af = P.Af[dir];
  const bf16* __restrict__ Bmt = P.Bmt[dir];
  const bf16* __restrict__ Wh1 = P.Wh1[dir];
  const float* __restrict__ bihp = P.bih[dir];
  const float* __restrict__ bhhp = P.bhh[dir];
  const float* __restrict__ c0v = P.c0[dir];
  const float* __restrict__ ahbp = P.ahb[dir];
  bf16* __restrict__ hhB = P.hh[dir];
  bf16* __restrict__ hbB = P.hb[dir];
  bf16* __restrict__ Up = P.Up[dir];
  float* __restrict__ cst = P.cst[dir];
  unsigned* __restrict__ flg = P.flags + (size_t)dir * 128 * 64;

  __shared__ float gl[4][16][33];
  __shared__ bf16 hs[32][16];           // this block's h j-slice (for U partials)
  __shared__ float h_lds[512];
  __shared__ float w_part[4][64];
  __shared__ float p_lds[64];

  unsigned ep = 0;
  const int lr16 = lane & 15;
  const int kb = lane >> 4;
  const int koff = kb * 8;

  // prefetched h_{t-1} A-fragments (rows lr16, lr16+16), registers
  short8b pA0[16], pA1[16];
  {
    const bf16* A0 = hbB + (size_t)lr16 * 512;           // slot 0 = h_{-1}
    const bf16* A1 = hbB + (size_t)(lr16 + 16) * 512;
#pragma unroll
    for (int ks = 0; ks < 16; ++ks) {
      pA0[ks] = ldb8(A0 + ks * 32 + koff);
      pA1[ks] = ldb8(A1 + ks * 32 + koff);
    }
  }

  for (int t = 0; t < 64; ++t) {
    const bf16* hhR = hhB + (size_t)t * 32 * 512;        // hhat_{t-1}
    bf16* hhW = hhB + (size_t)(t + 1) * 32 * 512;
    bf16* hbW = hbB + (size_t)(t + 1) * 32 * 512;        // h_t (written below)

    // ---------- Phase A: gates (MFMA) + LSTM cell + U-partials ----------
    {
      const int gate = wv;                   // wave 0..3 -> i,f,g,o
      const int gc = gate * 512 + g * 16 + lr16;
      const bf16* Brow = Wrec + (size_t)gc * 1024;
      const bf16* A0h = hhR + (size_t)lr16 * 512;
      const bf16* A1h = hhR + (size_t)(lr16 + 16) * 512;
      f32x4 ac0 = (f32x4){0.f, 0.f, 0.f, 0.f};
      f32x4 ac1 = (f32x4){0.f, 0.f, 0.f, 0.f};
#pragma unroll
      for (int ks = 0; ks < 16; ++ks) {      // h part (prefetched regs)
        const int k = ks * 32 + koff;
        const short8b bv = ldb8(Brow + 512 + k);
        ac0 = MFMA(pA0[ks], bv, ac0);
        ac1 = MFMA(pA1[ks], bv, ac1);
      }
#pragma unroll
      for (int c = 0; c < 2; ++c) {          // hhat part, staged 8-deep
        short8b sa[8], sb[8];
#pragma unroll
        for (int i = 0; i < 8; ++i) {
          const int k = (c * 8 + i) * 32 + koff;
          sa[i] = ldb8(A0h + k);
          sb[i] = ldb8(A1h + k);
        }
#pragma unroll
        for (int i = 0; i < 8; ++i) {
          const int k = (c * 8 + i) * 32 + koff;
          const short8b bv = ldb8(Brow + k);
          ac0 = MFMA(sa[i], bv, ac0);
          ac1 = MFMA(sb[i], bv, ac1);
        }
      }
      const int tcol = dir ? (63 - t) : t;
      const float bsum = bihp[gc] + bhhp[gc];
      const bf16* xpc = Xp + (size_t)gc * 2048 + tcol * 32;
#pragma unroll
      for (int r = 0; r < 4; ++r) {
        const int brow = kb * 4 + r;   // D: row=(lane>>4)*4+reg (batch), col=lane&15 (gc)
        gl[gate][lr16][brow] = ac0[r] + b2f(xpc[brow]) + bsum;
        gl[gate][lr16][brow + 16] = ac1[r] + b2f(xpc[brow + 16]) + bsum;
      }
    }
    __syncthreads();
    {
      const int b = tid & 31;
      const int jp = (tid >> 5) * 2;         // two consecutive j per thread
      float hn2[2];
#pragma unroll
      for (int u = 0; u < 2; ++u) {
        const int jl = jp + u;
        const int j = g * 16 + jl;
        const float gi = gl[0][jl][b];
        const float gf = gl[1][jl][b];
        const float gg = gl[2][jl][b];
        const float go = gl[3][jl][b];
        float cn = sigm(gf) * cst[j * 32 + b] + sigm(gi) * tanhf(gg);
        float hn = sigm(go) * tanhf(cn);
        if (dir) {
          const float m = P.mask[b * 64 + (63 - t)];
          hn *= m; cn *= m;
        }
        cst[j * 32 + b] = cn;                               // block-private
        hn2[u] = hn;
      }
      st4_wt(hbW + (size_t)b * 512 + g * 16 + jp, hn2[0], hn2[1]);
      *reinterpret_cast<unsigned*>(&hs[b][jp]) = pack2(hn2[0], hn2[1]);
    }
    __syncthreads();
    {
      // U-partials: Up[b][o][g] = Wh1[o, g*16..+16] . hs[b][:]  (K=16, padded)
      short8b hx0 = {0, 0, 0, 0, 0, 0, 0, 0};
      short8b hx1 = {0, 0, 0, 0, 0, 0, 0, 0};
      if (kb < 2) {
        hx0 = *reinterpret_cast<const short8b*>(&hs[lr16][kb * 8]);
        hx1 = *reinterpret_cast<const short8b*>(&hs[lr16 + 16][kb * 8]);
      }
      const f32x4 zac = (f32x4){0.f, 0.f, 0.f, 0.f};
#pragma unroll
      for (int oi = 0; oi < 8; ++oi) {
        const int og = wv + oi * 4;          // wave's o-groups cover 0..31
        short8b yv = {0, 0, 0, 0, 0, 0, 0, 0};
        if (kb < 2)
          yv = ldb8(Wh1 + (size_t)(og * 16 + lr16) * 512 + g * 16 + kb * 8);
        const f32x4 u0 = MFMA(yv, hx0, zac);   // D[row=o-in-grp, col=b]
        const f32x4 u1 = MFMA(yv, hx1, zac);
#pragma unroll
        for (int r = 0; r < 4; ++r) {
          const int oo = og * 16 + kb * 4 + r;
          st2_wt(Up + ((size_t)lr16 * 512 + oo) * 32 + g, u0[r]);
          st2_wt(Up + ((size_t)(lr16 + 16) * 512 + oo) * 32 + g, u1[r]);
        }
      }
    }
    gbar32(flg, ep++, g, tid);

    // ---------- Phase B: attention + a2 + U-sum + hhat, batch g ----------
    if (tid < 64) {
      const short8b v = ldb8(hbW + (size_t)g * 512 + tid * 8);  // h_t[g,:] -> LDS
#pragma unroll
      for (int e = 0; e < 8; ++e) h_lds[tid * 8 + e] = s2f(v[e]);
    }
    __syncthreads();
    {
      const int q = wv;
      const bf16* arow = Af + (size_t)(g * 64 + lane) * 512 + q * 128;
      float part = 0.f;
#pragma unroll 8
      for (int k8 = 0; k8 < 128; k8 += 8) {
        const short8b v = ldb8(arow + k8);
#pragma unroll
        for (int e = 0; e < 8; ++e) part += h_lds[q * 128 + k8 + e] * s2f(v[e]);
      }
      w_part[q][lane] = part;
    }
    __syncthreads();
    if (wv == 3) {
      const float v = (w_part[0][lane] + w_part[1][lane] + w_part[2][lane] +
                       w_part[3][lane]) * SCALE_F + c0v[g * 64 + lane];
      float mx = v;
#pragma unroll
      for (int d = 1; d < 64; d <<= 1) mx = fmaxf(mx, __shfl_xor(mx, d));
      const float e = expf(v - mx);
      float sm = e;
#pragma unroll
      for (int d = 1; d < 64; d <<= 1) sm += __shfl_xor(sm, d);
      p_lds[lane] = e / sm;
    }
    __syncthreads();
    {
      const int o2 = tid * 2;
      // U = sum of 32 partials, rows Up[g][o2][:] and Up[g][o2+1][:]
      u32x4 q0, q1, q2, q3, q4, q5, q6, q7;
      const bf16* pu0 = Up + ((size_t)g * 512 + o2) * 32;
      const bf16* pu1 = pu0 + 32;
      ld_up_rows(pu0, pu1, q0, q1, q2, q3, q4, q5, q6, q7);
      float u0 = 0.f, u1 = 0.f;
#pragma unroll
      for (int i = 0; i < 4; ++i) {
        u0 += s2f((short)(q0[i] & 0xffffu)) + s2f((short)(q0[i] >> 16));
        u0 += s2f((short)(q1[i] & 0xffffu)) + s2f((short)(q1[i] >> 16));
        u0 += s2f((short)(q2[i] & 0xffffu)) + s2f((short)(q2[i] >> 16));
        u0 += s2f((short)(q3[i] & 0xffffu)) + s2f((short)(q3[i] >> 16));
        u1 += s2f((short)(q4[i] & 0xffffu)) + s2f((short)(q4[i] >> 16));
        u1 += s2f((short)(q5[i] & 0xffffu)) + s2f((short)(q5[i] >> 16));
        u1 += s2f((short)(q6[i] & 0xffffu)) + s2f((short)(q6[i] >> 16));
        u1 += s2f((short)(q7[i] & 0xffffu)) + s2f((short)(q7[i] >> 16));
      }
      // a2 = ahb + p . Bm (Bmt rows s-contiguous)
      float s0 = ahbp[o2], s1 = ahbp[o2 + 1];
      {
        const bf16* bm0 = Bmt + ((size_t)g * 512 + o2) * 64;
        short8b v0[8], v1[8];
#pragma unroll
        for (int i = 0; i < 8; ++i) {
          v0[i] = ldb8(bm0 + i * 8);
          v1[i] = ldb8(bm0 + 64 + i * 8);
        }
#pragma unroll
        for (int i = 0; i < 8; ++i)
#pragma unroll
          for (int e = 0; e < 8; ++e) {
            const float p = p_lds[i * 8 + e];
            s0 += p * s2f(v0[i][e]);
            s1 += p * s2f(v1[i][e]);
          }
      }
      const float h0 = tanhf(u0 + s0);
      const float h1 = tanhf(u1 + s1);
      st4_wt(hhW + (size_t)g * 512 + o2, h0, h1);
      const unsigned hp = pack2(h0, h1);
      if (dir == 0) {
        *reinterpret_cast<unsigned*>(P.hcat + (size_t)(g * 64 + t) * 1024 + o2) = hp;
      } else if (t >= 2) {
        *reinterpret_cast<unsigned*>(P.hcat + (size_t)(g * 64 + t - 2) * 1024 + 512 + o2) = hp;
      }
      if (t < 63) {                            // prefetch h_t frags for next Phase A
        const bf16* A0 = hbW + (size_t)lr16 * 512;
        const bf16* A1 = hbW + (size_t)(lr16 + 16) * 512;
#pragma unroll
        for (int ks = 0; ks < 16; ++ks) {
          pA0[ks] = ldb8(A0 + ks * 32 + koff);
          pA1[ks] = ldb8(A1 + ks * 32 + koff);
        }
      }
    }
    gbar32(flg, ep++, g, tid);
  }
}

// =======================  host  =======================
extern "C" void kernel_launch(void* const* d_in, const int* in_sizes, int n_in,
                              void* d_out, int out_size, void* d_ws, size_t ws_size,
                              hipStream_t stream) {
  (void)in_sizes; (void)n_in; (void)out_size; (void)ws_size;
  const float* src  = (const float*)d_in[0];
  const int*   trg  = (const int*)d_in[1];
  const float* mask = (const float*)d_in[2];
  const float* emb  = (const float*)d_in[3];
  const float* fWih = (const float*)d_in[4];
  const float* fWhh = (const float*)d_in[5];
  const float* fbih = (const float*)d_in[6];
  const float* fbhh = (const float*)d_in[7];
  const float* bWih = (const float*)d_in[8];
  const float* bWhh = (const float*)d_in[9];
  const float* bbih = (const float*)d_in[10];
  const float* bbhh = (const float*)d_in[11];
  const float* fattW = (const float*)d_in[12];
  const float* fattb = (const float*)d_in[13];
  const float* battW = (const float*)d_in[14];
  const float* battb = (const float*)d_in[15];
  const float* fahW = (const float*)d_in[16];
  const float* fahb = (const float*)d_in[17];
  const float* bahW = (const float*)d_in[18];
  const float* bahb = (const float*)d_in[19];
  const float* fcW  = (const float*)d_in[20];
  const float* fcb  = (const float*)d_in[21];
  const float* feed = (const float*)d_in[22];
  const float* hid  = (const float*)d_in[23];

  char* wsp = (char*)d_ws;
  size_t off = 0;
  auto alloc = [&](size_t bytes) -> void* {
    void* p = wsp + off;
    off += (bytes + 255) & ~(size_t)255;
    return p;
  };
  unsigned* flags = (unsigned*)alloc((size_t)2 * 128 * 64 * 4);
  bf16* hcat = (bf16*)alloc((size_t)2048 * 1024 * 2);
  const size_t zero_bytes = off;                 // flags + hcat zeroed per launch
  bf16* xg    = (bf16*)alloc((size_t)2048 * 512 * 2);
  bf16* srcb  = (bf16*)alloc((size_t)2048 * 1024 * 2);
  bf16* fcWb  = (bf16*)alloc((size_t)32000 * 1024 * 2);
  bf16* Wxf   = (bf16*)alloc((size_t)2048 * 512 * 2);
  bf16* Wxb   = (bf16*)alloc((size_t)2048 * 512 * 2);
  bf16* Wrecf = (bf16*)alloc((size_t)2048 * 1024 * 2);
  bf16* Wrecb = (bf16*)alloc((size_t)2048 * 1024 * 2);
  bf16* attWtf = (bf16*)alloc((size_t)512 * 1024 * 2);
  bf16* attWtb = (bf16*)alloc((size_t)512 * 1024 * 2);
  bf16* ahW2f = (bf16*)alloc((size_t)512 * 1024 * 2);
  bf16* ahW2b = (bf16*)alloc((size_t)512 * 1024 * 2);
  bf16* Wh1f  = (bf16*)alloc((size_t)512 * 512 * 2);
  bf16* Wh1b  = (bf16*)alloc((size_t)512 * 512 * 2);
  bf16* Xpf   = (bf16*)alloc((size_t)2048 * 2048 * 2);
  bf16* Xpb   = (bf16*)alloc((size_t)2048 * 2048 * 2);
  bf16* Aff   = (bf16*)alloc((size_t)2048 * 512 * 2);
  bf16* Afb   = (bf16*)alloc((size_t)2048 * 512 * 2);
  bf16* Bmf   = (bf16*)alloc((size_t)2048 * 512 * 2);
  bf16* Bmb   = (bf16*)alloc((size_t)2048 * 512 * 2);
  bf16* Bmtf  = (bf16*)alloc((size_t)2048 * 512 * 2);
  bf16* Bmtb  = (bf16*)alloc((size_t)2048 * 512 * 2);
  bf16* Upf   = (bf16*)alloc((size_t)32 * 512 * 32 * 2);   // [b][o][g]
  bf16* Upb   = (bf16*)alloc((size_t)32 * 512 * 32 * 2);
  float* c0f  = (float*)alloc(2048 * 4);
  float* c0b  = (float*)alloc(2048 * 4);
  bf16* hh0   = (bf16*)alloc((size_t)65 * 32 * 512 * 2);
  bf16* hh1   = (bf16*)alloc((size_t)65 * 32 * 512 * 2);
  bf16* hb0   = (bf16*)alloc((size_t)65 * 32 * 512 * 2);
  bf16* hb1   = (bf16*)alloc((size_t)65 * 32 * 512 * 2);
  float* cst0 = (float*)alloc((size_t)512 * 32 * 4);
  float* cst1 = (float*)alloc((size_t)512 * 32 * 4);

  hipMemsetAsync(d_ws, 0, zero_bytes, stream);

  k_xg<<<4096, 256, 0, stream>>>(emb, trg, xg);
  k_srcb<<<8192, 256, 0, stream>>>(src, srcb);
  k_fcw<<<8192, 256, 0, stream>>>(fcW, fcWb);
  k_wpack<<<2048, 256, 0, stream>>>(fWih, fWhh, bWih, bWhh, fattW, battW, bahW, fahW,
                                    Wxf, Wxb, Wrecf, Wrecb, attWtf, attWtb, ahW2f, ahW2b,
                                    Wh1f, Wh1b);
  k_c0<<<2048, 256, 0, stream>>>(src, fattb, battb, c0f, c0b);
  k_init<<<64, 256, 0, stream>>>(feed, hid, hh0, hh1, hb0, hb1, cst0, cst1);

  // Xp[gc][r] = (x @ Wih_x^T)^T  (gc-major so scan reads are b-coalesced)
  gemm_k<bf16, false><<<dim3(16, 16), 256, 0, stream>>>(Wxf, xg, Xpf, nullptr, 2048, 2048, 512);
  gemm_k<bf16, false><<<dim3(16, 16), 256, 0, stream>>>(Wxb, xg, Xpb, nullptr, 2048, 2048, 512);
  // A[r][j] = src @ attW ;  Bm[r][o] = src @ ahW_ct^T
  gemm_k<bf16, false><<<dim3(4, 16), 256, 0, stream>>>(srcb, attWtf, Aff, nullptr, 2048, 512, 1024);
  gemm_k<bf16, false><<<dim3(4, 16), 256, 0, stream>>>(srcb, attWtb, Afb, nullptr, 2048, 512, 1024);
  gemm_k<bf16, false><<<dim3(4, 16), 256, 0, stream>>>(srcb, ahW2f, Bmf, nullptr, 2048, 512, 1024);
  gemm_k<bf16, false><<<dim3(4, 16), 256, 0, stream>>>(srcb, ahW2b, Bmb, nullptr, 2048, 512, 1024);
  k_bmt<<<4096, 256, 0, stream>>>(Bmf, Bmtf);
  k_bmt<<<4096, 256, 0, stream>>>(Bmb, Bmtb);

  ScanP sp;
  sp.Wrec[0] = Wrecf; sp.Wrec[1] = Wrecb;
  sp.Xp[0] = Xpf;     sp.Xp[1] = Xpb;
  sp.Af[0] = Aff;     sp.Af[1] = Afb;
  sp.Bmt[0] = Bmtf;   sp.Bmt[1] = Bmtb;
  sp.Wh1[0] = Wh1f;   sp.Wh1[1] = Wh1b;
  sp.bih[0] = fbih;   sp.bih[1] = bbih;
  sp.bhh[0] = fbhh;   sp.bhh[1] = bbhh;
  sp.c0[0] = c0f;     sp.c0[1] = c0b;
  sp.ahb[0] = bahb;   sp.ahb[1] = fahb;   // att_hidden weights are swapped in the reference
  sp.mask = mask;
  sp.hh[0] = hh0;     sp.hh[1] = hh1;
  sp.hb[0] = hb0;     sp.hb[1] = hb1;
  sp.Up[0] = Upf;     sp.Up[1] = Upb;
  sp.cst[0] = cst0;   sp.cst[1] = cst1;
  sp.hcat = hcat;     sp.flags = flags;
  scan_k<<<64, 256, 0, stream>>>(sp);

  // logits[b*64+t][v] = hcat @ fcW^T + fcb  (LDS-staged)
  gemm_out<<<4000, 256, 0, stream>>>(hcat, fcWb, (float*)d_out, fcb);
}

// Round 12
// 2940.889 us; speedup vs baseline: 1.3214x; 1.3214x over previous
//
#include <hip/hip_runtime.h>
#include <hip/hip_bf16.h>
#include <math.h>

typedef __hip_bfloat16 bf16;
typedef __attribute__((ext_vector_type(8))) short short8b;
typedef __attribute__((ext_vector_type(8))) __bf16 bf16x8;
typedef __attribute__((ext_vector_type(4))) float f32x4;

#define SCALE_F 0.04419417382415922f  // 1/sqrt(512)

// ---- MFMA wrapper tolerant of either builtin signature (v8i16 or v8bf16) ----
template <typename V>
static __device__ inline auto mfma_try(V a, V b, f32x4 c, int)
    -> decltype(__builtin_amdgcn_mfma_f32_16x16x32_bf16(a, b, c, 0, 0, 0)) {
  return __builtin_amdgcn_mfma_f32_16x16x32_bf16(a, b, c, 0, 0, 0);
}
template <typename V>
static __device__ inline auto mfma_try(V a, V b, f32x4 c, long)
    -> decltype(__builtin_amdgcn_mfma_f32_16x16x32_bf16(
        __builtin_bit_cast(bf16x8, a), __builtin_bit_cast(bf16x8, b), c, 0, 0, 0)) {
  return __builtin_amdgcn_mfma_f32_16x16x32_bf16(
      __builtin_bit_cast(bf16x8, a), __builtin_bit_cast(bf16x8, b), c, 0, 0, 0);
}
static __device__ inline f32x4 MFMA(short8b a, short8b b, f32x4 c) {
  return mfma_try(a, b, c, 0);
}

static __device__ inline short8b ldb8(const bf16* p) {
  return *reinterpret_cast<const short8b*>(p);
}
static __device__ inline float b2f(bf16 v) { return __bfloat162float(v); }
static __device__ inline bf16 f2b(float v) { return __float2bfloat16(v); }
static __device__ inline float s2f(short s) {
  unsigned u = ((unsigned)(unsigned short)s) << 16;
  return __builtin_bit_cast(float, u);
}
static __device__ inline unsigned pack2(float lo, float hi) {
  const unsigned a = (unsigned)__builtin_bit_cast(unsigned short, f2b(lo));
  const unsigned b = (unsigned)__builtin_bit_cast(unsigned short, f2b(hi));
  return a | (b << 16);
}
static __device__ inline float sigm(float x) { return 1.f / (1.f + expf(-x)); }

// write-through stores: bypass L1/L2, land at the LLC (device coherence
// point) -> cross-XCD visible without cache-wide fence ops. (R4-proven.)
static __device__ inline void st2_wt(bf16* p, float v) {
  unsigned ud = (unsigned)__builtin_bit_cast(unsigned short, f2b(v));
  asm volatile("global_store_short %0, %1, off sc0 sc1" ::"v"(p), "v"(ud)
               : "memory");
}
static __device__ inline void st4_wt(bf16* p, float lo, float hi) {
  unsigned ud = pack2(lo, hi);
  asm volatile("global_store_dword %0, %1, off sc0 sc1" ::"v"(p), "v"(ud)
               : "memory");
}

static __device__ inline void st_flag(unsigned* p, unsigned v) {
  asm volatile("global_store_dword %0, %1, off sc0 sc1" ::"v"(p), "v"(v)
               : "memory");
}
static __device__ inline unsigned ld_flag(const unsigned* p) {
  unsigned v;
  asm volatile("global_load_dword %0, %1, off sc0 sc1\n\ts_waitcnt vmcnt(0)"
               : "=v"(v)
               : "v"(p)
               : "memory");
  return v;
}

// ---- contention-free LLC flag barrier (R4-proven) ----
static __device__ inline void gbar(unsigned* flags, unsigned ep, int blk, int tid) {
  asm volatile("s_waitcnt vmcnt(0)" ::: "memory");
  __syncthreads();
  if (tid < 64) {
    unsigned* row = flags + (size_t)ep * 64;
    if (tid == 0) st_flag(row + blk, 1u);
    while (true) {
      const unsigned v = ld_flag(row + tid);
      if (__ballot(v != 0) == ~0ull) break;
      __builtin_amdgcn_s_sleep(1);
    }
  }
  __syncthreads();
}

// =======================  generic MFMA GEMM (prep)  =======================
template <typename OutT, bool HAS_BIAS>
__global__ __launch_bounds__(256) void gemm_k(
    const bf16* __restrict__ A, const bf16* __restrict__ Bw,
    OutT* __restrict__ C, const float* __restrict__ bias,
    int M, int N, int K) {
  const int lane = threadIdx.x & 63;
  const int wid = threadIdx.x >> 6;
  const int m0 = blockIdx.y * 128 + (wid >> 1) * 64;
  const int n0 = blockIdx.x * 128 + (wid & 1) * 64;
  const int lr = lane & 15;
  const int lk = (lane >> 4) * 8;
  f32x4 acc[4][4];
#pragma unroll
  for (int i = 0; i < 4; ++i)
#pragma unroll
    for (int j = 0; j < 4; ++j) acc[i][j] = (f32x4){0.f, 0.f, 0.f, 0.f};
  const bf16* Ap = A + (size_t)(m0 + lr) * K + lk;
  const bf16* Bp = Bw + (size_t)(n0 + lr) * K + lk;
  for (int k0 = 0; k0 < K; k0 += 32) {
    short8b av[4], bv[4];
#pragma unroll
    for (int i = 0; i < 4; ++i) av[i] = ldb8(Ap + (size_t)i * 16 * K + k0);
#pragma unroll
    for (int i = 0; i < 4; ++i) bv[i] = ldb8(Bp + (size_t)i * 16 * K + k0);
#pragma unroll
    for (int mi = 0; mi < 4; ++mi)
#pragma unroll
      for (int ni = 0; ni < 4; ++ni)
        acc[mi][ni] = MFMA(av[mi], bv[ni], acc[mi][ni]);
  }
  const int rb = (lane >> 4) * 4;
#pragma unroll
  for (int mi = 0; mi < 4; ++mi) {
#pragma unroll
    for (int r = 0; r < 4; ++r) {
      const int row = m0 + mi * 16 + rb + r;
#pragma unroll
      for (int ni = 0; ni < 4; ++ni) {
        const int col = n0 + ni * 16 + lr;
        float v = acc[mi][ni][r];
        if (HAS_BIAS) v += bias[col];
        if constexpr (sizeof(OutT) == 2) {
          C[(size_t)row * N + col] = f2b(v);
        } else {
          C[(size_t)row * N + col] = v;
        }
      }
    }
  }
}

// Output GEMM M=2048 N=32000 K=1024, LDS-staged (128x128 tile, BK=32,
// reg-staged global->LDS, 2 barriers/K-step, ds_read_b128 frags). (R11-proven)
__global__ __launch_bounds__(256) void gemm_out(
    const bf16* __restrict__ A, const bf16* __restrict__ Bw,
    float* __restrict__ C, const float* __restrict__ bias) {
  constexpr int K = 1024, N = 32000;
  __shared__ bf16 As[128 * 32];
  __shared__ bf16 Bs[128 * 32];
  const int wgid = blockIdx.x;            // 4000 = 16 m x 250 n, m fastest
  const int mt = wgid & 15, nt = wgid >> 4;
  const int tid = threadIdx.x, lane = tid & 63, wv = tid >> 6;
  const int m0 = mt * 128, n0 = nt * 128;
  const int lr16 = lane & 15, kb = lane >> 4, koff = kb * 8;
  const int r0 = tid >> 2, q0 = tid & 3;
  const int r1 = (tid + 256) >> 2;
  const bf16* Ap0 = A + (size_t)(m0 + r0) * K + q0 * 8;
  const bf16* Ap1 = A + (size_t)(m0 + r1) * K + q0 * 8;
  const bf16* Bp0 = Bw + (size_t)(n0 + r0) * K + q0 * 8;
  const bf16* Bp1 = Bw + (size_t)(n0 + r1) * K + q0 * 8;
  const int wm = (wv >> 1) * 64, wn = (wv & 1) * 64;
  f32x4 acc[4][4];
#pragma unroll
  for (int i = 0; i < 4; ++i)
#pragma unroll
    for (int j = 0; j < 4; ++j) acc[i][j] = (f32x4){0.f, 0.f, 0.f, 0.f};
  short8b a0 = ldb8(Ap0), a1 = ldb8(Ap1), b0 = ldb8(Bp0), b1 = ldb8(Bp1);
  for (int k0 = 0; k0 < K; k0 += 32) {
    __syncthreads();
    *reinterpret_cast<short8b*>(&As[tid * 8]) = a0;
    *reinterpret_cast<short8b*>(&As[(tid + 256) * 8]) = a1;
    *reinterpret_cast<short8b*>(&Bs[tid * 8]) = b0;
    *reinterpret_cast<short8b*>(&Bs[(tid + 256) * 8]) = b1;
    __syncthreads();
    if (k0 + 32 < K) {
      a0 = ldb8(Ap0 + k0 + 32);
      a1 = ldb8(Ap1 + k0 + 32);
      b0 = ldb8(Bp0 + k0 + 32);
      b1 = ldb8(Bp1 + k0 + 32);
    }
    short8b af[4], bfr[4];
#pragma unroll
    for (int i = 0; i < 4; ++i) {
      af[i] = *reinterpret_cast<const short8b*>(&As[(wm + i * 16 + lr16) * 32 + koff]);
      bfr[i] = *reinterpret_cast<const short8b*>(&Bs[(wn + i * 16 + lr16) * 32 + koff]);
    }
#pragma unroll
    for (int mi = 0; mi < 4; ++mi)
#pragma unroll
      for (int ni = 0; ni < 4; ++ni)
        acc[mi][ni] = MFMA(af[mi], bfr[ni], acc[mi][ni]);
  }
#pragma unroll
  for (int mi = 0; mi < 4; ++mi) {
#pragma unroll
    for (int r = 0; r < 4; ++r) {
      const int row = m0 + wm + mi * 16 + kb * 4 + r;
#pragma unroll
      for (int ni = 0; ni < 4; ++ni) {
        const int col = n0 + wn + ni * 16 + lr16;
        C[(size_t)row * N + col] = acc[mi][ni][r] + bias[col];
      }
    }
  }
}

// =======================  prep kernels  =======================
__global__ void k_xg(const float* __restrict__ emb, const int* __restrict__ trg,
                     bf16* __restrict__ xg) {
  const int i = blockIdx.x * 256 + threadIdx.x;   // 2048*512 exact
  const int r = i >> 9, e = i & 511;
  const int t = r >> 5, b = r & 31;
  const int tok = trg[b * 64 + t];
  xg[i] = f2b(emb[(size_t)tok * 512 + e]);
}

__global__ void k_srcb(const float* __restrict__ s, bf16* __restrict__ d) {
  const int i = blockIdx.x * 256 + threadIdx.x;   // 2048*1024 exact
  d[i] = f2b(s[i]);
}

__global__ void k_fcw(const float* __restrict__ s, bf16* __restrict__ d) {
  const size_t stride = (size_t)gridDim.x * blockDim.x;
  for (size_t i = blockIdx.x * (size_t)blockDim.x + threadIdx.x;
       i < (size_t)32000 * 1024; i += stride)
    d[i] = f2b(s[i]);
}

// Bm[b*64+s][o] -> Bmt[b][o][s]  (dense s-contiguous rows for the a2 dot)
__global__ void k_bmt(const bf16* __restrict__ in, bf16* __restrict__ out) {
  const int i = blockIdx.x * 256 + threadIdx.x;   // 32*512*64 = 1048576 exact
  const int b = i >> 15, rem = i & 32767, o = rem >> 6, s = rem & 63;
  out[i] = in[(size_t)(b * 64 + s) * 512 + o];
}

__global__ void k_wpack(const float* __restrict__ fWih, const float* __restrict__ fWhh,
                        const float* __restrict__ bWih, const float* __restrict__ bWhh,
                        const float* __restrict__ fattW, const float* __restrict__ battW,
                        const float* __restrict__ bahW, const float* __restrict__ fahW,
                        bf16* Wxf, bf16* Wxb, bf16* Wrecf, bf16* Wrecb,
                        bf16* attWtf, bf16* attWtb, bf16* ahW2f, bf16* ahW2b,
                        bf16* Wh1f, bf16* Wh1b) {
  const int stride = gridDim.x * blockDim.x;
  const int i0 = blockIdx.x * blockDim.x + threadIdx.x;
  for (int i = i0; i < 2048 * 512; i += stride) {        // Wih x-slice
    const int gc = i >> 9, k = i & 511;
    Wxf[i] = f2b(fWih[(size_t)gc * 1024 + k]);
    Wxb[i] = f2b(bWih[(size_t)gc * 1024 + k]);
  }
  for (int i = i0; i < 2048 * 1024; i += stride) {       // [Wih_h | Whh]
    const int gc = i >> 10, k = i & 1023;
    float vf, vb;
    if (k < 512) { vf = fWih[(size_t)gc * 1024 + 512 + k]; vb = bWih[(size_t)gc * 1024 + 512 + k]; }
    else         { vf = fWhh[(size_t)gc * 512 + k - 512]; vb = bWhh[(size_t)gc * 512 + k - 512]; }
    Wrecf[i] = f2b(vf); Wrecb[i] = f2b(vb);
  }
  for (int i = i0; i < 512 * 1024; i += stride) {        // attW transpose
    const int j = i >> 10, d = i & 1023;
    attWtf[i] = f2b(fattW[(size_t)d * 512 + j]);
    attWtb[i] = f2b(battW[(size_t)d * 512 + j]);
  }
  for (int i = i0; i < 512 * 1024; i += stride) {        // ah_W ct-slice (swapped: fwd uses bah)
    const int o = i >> 10, d = i & 1023;
    ahW2f[i] = f2b(bahW[(size_t)o * 1536 + 512 + d]);
    ahW2b[i] = f2b(fahW[(size_t)o * 1536 + 512 + d]);
  }
  for (int i = i0; i < 512 * 512; i += stride) {         // ah_W h-slice bf16 [o][k]
    const int o = i >> 9, k = i & 511;
    Wh1f[i] = f2b(bahW[(size_t)o * 1536 + k]);
    Wh1b[i] = f2b(fahW[(size_t)o * 1536 + k]);
  }
}

__global__ void k_c0(const float* __restrict__ src, const float* __restrict__ fb,
                     const float* __restrict__ bb, float* __restrict__ c0f,
                     float* __restrict__ c0b) {
  const int r = blockIdx.x;
  const int tid = threadIdx.x;
  float pf = 0.f, pb = 0.f;
  for (int d = tid; d < 1024; d += 256) {
    const float s = src[(size_t)r * 1024 + d];
    pf += s * fb[d];
    pb += s * bb[d];
  }
#pragma unroll
  for (int d = 1; d < 64; d <<= 1) { pf += __shfl_xor(pf, d); pb += __shfl_xor(pb, d); }
  __shared__ float rf[4], rb2[4];
  if ((tid & 63) == 0) { rf[tid >> 6] = pf; rb2[tid >> 6] = pb; }
  __syncthreads();
  if (tid == 0) {
    c0f[r] = (rf[0] + rf[1] + rf[2] + rf[3]) * SCALE_F;
    c0b[r] = (rb2[0] + rb2[1] + rb2[2] + rb2[3]) * SCALE_F;
  }
}

// rolling state buffers per dir: hh[65][32][512], hb[65][32][512] bf16
__global__ void k_init(const float* __restrict__ feed, const float* __restrict__ hid,
                       bf16* hh0, bf16* hh1, bf16* hb0, bf16* hb1,
                       float* cst0, float* cst1) {
  const int i = blockIdx.x * 256 + threadIdx.x;   // 32*512 exact
  const int b = i >> 9, k = i & 511;
  hh0[i] = f2b(feed[k]);
  hh1[i] = f2b(feed[512 + k]);
  hb0[i] = f2b(hid[k]);
  hb1[i] = f2b(hid[1024 + k]);
  cst0[k * 32 + b] = hid[512 + k];
  cst1[k * 32 + b] = hid[1536 + k];
}

// =======================  sequential scan (R8 3-phase + x-fold)  ==============
struct ScanP {
  const bf16* Wrec[2]; const bf16* Wx[2]; const bf16* xg;
  const bf16* Af[2]; const bf16* Bmt[2]; const bf16* Wh1[2];
  const float* bih[2]; const float* bhh[2];
  const float* c0[2]; const float* ahb[2]; const float* mask;
  bf16* hh[2]; bf16* hb[2]; bf16* U[2]; float* cst[2]; bf16* hcat; unsigned* flags;
};

__global__ __launch_bounds__(256) void scan_k(ScanP P) {
  const int blk = blockIdx.x;     // 64 blocks
  const int dir = blk >> 5;       // 0 fwd, 1 bwd
  const int g = blk & 31;         // PhaseA/B1: j-slice; PhaseB2/C: batch index
  const int tid = threadIdx.x;
  const int lane = tid & 63;
  const int wv = tid >> 6;

  const bf16* __restrict__ Wrec = P.Wrec[dir];
  const bf16* __restrict__ Wx = P.Wx[dir];
  const bf16* __restrict__ xg = P.xg;
  const bf16* __restrict__ Af = P.Af[dir];
  const bf16* __restrict__ Bmt = P.Bmt[dir];
  const bf16* __restrict__ Wh1 = P.Wh1[dir];
  const float* __restrict__ bihp = P.bih[dir];
  const float* __restrict__ bhhp = P.bhh[dir];
  const float* __restrict__ c0v = P.c0[dir];
  const float* __restrict__ ahbp = P.ahb[dir];
  bf16* __restrict__ hhB = P.hh[dir];
  bf16* __restrict__ hbB = P.hb[dir];
  bf16* __restrict__ Ubuf = P.U[dir];
  float* __restrict__ cst = P.cst[dir];

  __shared__ float gl[4][16][33];
  __shared__ float h_lds[512];
  __shared__ float w_part[2][64];
  __shared__ float p_lds[64];

  unsigned ep = 0;
  const int lr16 = lane & 15;
  const int kb = lane >> 4;
  const int koff = kb * 8;

  // prefetched h_{t-1} A-fragments (rows lr16, lr16+16), registers
  short8b pA0[16], pA1[16];
  {
    const bf16* A0 = hbB + (size_t)lr16 * 512;           // slot 0 = h_{-1}
    const bf16* A1 = hbB + (size_t)(lr16 + 16) * 512;
#pragma unroll
    for (int ks = 0; ks < 16; ++ks) {
      pA0[ks] = ldb8(A0 + ks * 32 + koff);
      pA1[ks] = ldb8(A1 + ks * 32 + koff);
    }
  }

  for (int t = 0; t < 64; ++t) {
    const bf16* hhR = hhB + (size_t)t * 32 * 512;        // hhat_{t-1}
    bf16* hhW = hhB + (size_t)(t + 1) * 32 * 512;
    bf16* hbW = hbB + (size_t)(t + 1) * 32 * 512;        // h_t (written below)

    // ---------- Phase A: gates (MFMA, K=1536 over [hhat|h|x]) + LSTM cell ----------
    {
      const int gate = wv;                   // wave 0..3 -> i,f,g,o
      const int gc = gate * 512 + g * 16 + lr16;
      const int tcol = dir ? (63 - t) : t;
      const bf16* Brow = Wrec + (size_t)gc * 1024;
      const bf16* Bxrow = Wx + (size_t)gc * 512;
      const bf16* A0h = hhR + (size_t)lr16 * 512;
      const bf16* A1h = hhR + (size_t)(lr16 + 16) * 512;
      const bf16* A0x = xg + ((size_t)tcol * 32 + lr16) * 512;
      const bf16* A1x = A0x + (size_t)16 * 512;
      f32x4 ac0 = (f32x4){0.f, 0.f, 0.f, 0.f};
      f32x4 ac1 = (f32x4){0.f, 0.f, 0.f, 0.f};
#pragma unroll
      for (int ks = 0; ks < 16; ++ks) {      // h part (prefetched regs)
        const int k = ks * 32 + koff;
        const short8b bv = ldb8(Brow + 512 + k);
        ac0 = MFMA(pA0[ks], bv, ac0);
        ac1 = MFMA(pA1[ks], bv, ac1);
      }
#pragma unroll
      for (int c = 0; c < 2; ++c) {          // hhat part, staged 8-deep
        short8b sa[8], sb[8];
#pragma unroll
        for (int i = 0; i < 8; ++i) {
          const int k = (c * 8 + i) * 32 + koff;
          sa[i] = ldb8(A0h + k);
          sb[i] = ldb8(A1h + k);
        }
#pragma unroll
        for (int i = 0; i < 8; ++i) {
          const int k = (c * 8 + i) * 32 + koff;
          const short8b bv = ldb8(Brow + k);
          ac0 = MFMA(sa[i], bv, ac0);
          ac1 = MFMA(sb[i], bv, ac1);
        }
      }
#pragma unroll
      for (int c = 0; c < 2; ++c) {          // x part, staged 8-deep (folded GEMM)
        short8b sa[8], sb[8];
#pragma unroll
        for (int i = 0; i < 8; ++i) {
          const int k = (c * 8 + i) * 32 + koff;
          sa[i] = ldb8(A0x + k);
          sb[i] = ldb8(A1x + k);
        }
#pragma unroll
        for (int i = 0; i < 8; ++i) {
          const int k = (c * 8 + i) * 32 + koff;
          const short8b bv = ldb8(Bxrow + k);
          ac0 = MFMA(sa[i], bv, ac0);
          ac1 = MFMA(sb[i], bv, ac1);
        }
      }
      const float bsum = bihp[gc] + bhhp[gc];
#pragma unroll
      for (int r = 0; r < 4; ++r) {
        const int brow = kb * 4 + r;   // D: row=(lane>>4)*4+reg (batch), col=lane&15 (gc)
        gl[gate][lr16][brow] = ac0[r] + bsum;
        gl[gate][lr16][brow + 16] = ac1[r] + bsum;
      }
    }
    __syncthreads();
    {
      const int b = tid & 31;
      const int jp = (tid >> 5) * 2;         // two consecutive j per thread
      float hn2[2];
#pragma unroll
      for (int u = 0; u < 2; ++u) {
        const int jl = jp + u;
        const int j = g * 16 + jl;
        const float gi = gl[0][jl][b];
        const float gf = gl[1][jl][b];
        const float gg = gl[2][jl][b];
        const float go = gl[3][jl][b];
        float cn = sigm(gf) * cst[j * 32 + b] + sigm(gi) * tanhf(gg);
        float hn = sigm(go) * tanhf(cn);
        if (dir) {
          const float m = P.mask[b * 64 + (63 - t)];
          hn *= m; cn *= m;
        }
        cst[j * 32 + b] = cn;                               // block-private
        hn2[u] = hn;
      }
      st4_wt(hbW + (size_t)b * 512 + g * 16 + jp, hn2[0], hn2[1]);
    }
    gbar(P.flags, ep++, blk, tid);

    // ---------- Phase B: U (wave 0, j-slice) + attention (waves 1-3, batch g) ----------
    if (wv == 0) {
      // U[b, o-slice] = Wh1[o-slice,:] . h_t[b,:]   (MFMA, K=512)
      const bf16* Brow = Wh1 + (size_t)(g * 16 + lr16) * 512;
      const bf16* A0 = hbW + (size_t)lr16 * 512;
      const bf16* A1 = hbW + (size_t)(lr16 + 16) * 512;
      f32x4 u0 = (f32x4){0.f, 0.f, 0.f, 0.f};
      f32x4 u1 = (f32x4){0.f, 0.f, 0.f, 0.f};
#pragma unroll
      for (int ks = 0; ks < 16; ++ks) {
        const int k = ks * 32 + koff;
        const short8b bv = ldb8(Brow + k);
        u0 = MFMA(ldb8(A0 + k), bv, u0);
        u1 = MFMA(ldb8(A1 + k), bv, u1);
      }
      bf16* Uw = Ubuf + (size_t)t * 32 * 512;
      const int o = g * 16 + lr16;
#pragma unroll
      for (int r = 0; r < 4; ++r) {
        const int b0 = kb * 4 + r;
        st2_wt(Uw + (size_t)b0 * 512 + o, u0[r]);
        st2_wt(Uw + (size_t)(b0 + 16) * 512 + o, u1[r]);
      }
    } else if (wv == 1) {
      const short8b v = ldb8(hbW + (size_t)g * 512 + lane * 8);  // h_t[g,:] -> LDS
#pragma unroll
      for (int e = 0; e < 8; ++e) h_lds[lane * 8 + e] = s2f(v[e]);
    }
    __syncthreads();
    if (wv == 1 || wv == 2) {
      const int q = wv - 1;
      const bf16* arow = Af + (size_t)(g * 64 + lane) * 512 + q * 256;
      float part = 0.f;
#pragma unroll 8
      for (int k8 = 0; k8 < 256; k8 += 8) {
        const short8b v = ldb8(arow + k8);
#pragma unroll
        for (int e = 0; e < 8; ++e) part += h_lds[q * 256 + k8 + e] * s2f(v[e]);
      }
      w_part[q][lane] = part;
    }
    __syncthreads();
    if (wv == 3) {
      const float v = (w_part[0][lane] + w_part[1][lane]) * SCALE_F + c0v[g * 64 + lane];
      float mx = v;
#pragma unroll
      for (int d = 1; d < 64; d <<= 1) mx = fmaxf(mx, __shfl_xor(mx, d));
      const float e = expf(v - mx);
      float sm = e;
#pragma unroll
      for (int d = 1; d < 64; d <<= 1) sm += __shfl_xor(sm, d);
      p_lds[lane] = e / sm;
    }
    __syncthreads();
    // acc2 = ahb + p . Bm : thread owns o-pair; Bmt rows are s-contiguous.
    float a2[2];
    {
      const int o2 = tid * 2;
      const bf16* bm0 = Bmt + ((size_t)g * 512 + o2) * 64;
      short8b v0[8], v1[8];
#pragma unroll
      for (int i = 0; i < 8; ++i) {
        v0[i] = ldb8(bm0 + i * 8);
        v1[i] = ldb8(bm0 + 64 + i * 8);
      }
      float s0 = ahbp[o2], s1 = ahbp[o2 + 1];
#pragma unroll
      for (int i = 0; i < 8; ++i)
#pragma unroll
        for (int e = 0; e < 8; ++e) {
          const float p = p_lds[i * 8 + e];
          s0 += p * s2f(v0[i][e]);
          s1 += p * s2f(v1[i][e]);
        }
      a2[0] = s0; a2[1] = s1;
    }
    gbar(P.flags, ep++, blk, tid);

    // ---------- Phase C: hhat = tanh(U + acc2), batch g ----------
    {
      const int o2 = tid * 2;
      const unsigned uu =
          *reinterpret_cast<const unsigned*>(Ubuf + ((size_t)t * 32 + g) * 512 + o2);
      const float h0 = tanhf(a2[0] + s2f((short)(uu & 0xffffu)));
      const float h1 = tanhf(a2[1] + s2f((short)(uu >> 16)));
      st4_wt(hhW + (size_t)g * 512 + o2, h0, h1);
      const unsigned hp = pack2(h0, h1);
      if (dir == 0) {
        *reinterpret_cast<unsigned*>(P.hcat + (size_t)(g * 64 + t) * 1024 + o2) = hp;
      } else if (t >= 2) {
        *reinterpret_cast<unsigned*>(P.hcat + (size_t)(g * 64 + t - 2) * 1024 + 512 + o2) = hp;
      }
      if (t < 63) {                            // prefetch h_t frags for next Phase A
        const bf16* A0 = hbW + (size_t)lr16 * 512;
        const bf16* A1 = hbW + (size_t)(lr16 + 16) * 512;
#pragma unroll
        for (int ks = 0; ks < 16; ++ks) {
          pA0[ks] = ldb8(A0 + ks * 32 + koff);
          pA1[ks] = ldb8(A1 + ks * 32 + koff);
        }
      }
    }
    gbar(P.flags, ep++, blk, tid);
  }
}

// =======================  host  =======================
extern "C" void kernel_launch(void* const* d_in, const int* in_sizes, int n_in,
                              void* d_out, int out_size, void* d_ws, size_t ws_size,
                              hipStream_t stream) {
  (void)in_sizes; (void)n_in; (void)out_size; (void)ws_size;
  const float* src  = (const float*)d_in[0];
  const int*   trg  = (const int*)d_in[1];
  const float* mask = (const float*)d_in[2];
  const float* emb  = (const float*)d_in[3];
  const float* fWih = (const float*)d_in[4];
  const float* fWhh = (const float*)d_in[5];
  const float* fbih = (const float*)d_in[6];
  const float* fbhh = (const float*)d_in[7];
  const float* bWih = (const float*)d_in[8];
  const float* bWhh = (const float*)d_in[9];
  const float* bbih = (const float*)d_in[10];
  const float* bbhh = (const float*)d_in[11];
  const float* fattW = (const float*)d_in[12];
  const float* fattb = (const float*)d_in[13];
  const float* battW = (const float*)d_in[14];
  const float* battb = (const float*)d_in[15];
  const float* fahW = (const float*)d_in[16];
  const float* fahb = (const float*)d_in[17];
  const float* bahW = (const float*)d_in[18];
  const float* bahb = (const float*)d_in[19];
  const float* fcW  = (const float*)d_in[20];
  const float* fcb  = (const float*)d_in[21];
  const float* feed = (const float*)d_in[22];
  const float* hid  = (const float*)d_in[23];

  char* wsp = (char*)d_ws;
  size_t off = 0;
  auto alloc = [&](size_t bytes) -> void* {
    void* p = wsp + off;
    off += (bytes + 255) & ~(size_t)255;
    return p;
  };
  unsigned* flags = (unsigned*)alloc((size_t)192 * 64 * 4);
  bf16* hcat = (bf16*)alloc((size_t)2048 * 1024 * 2);
  const size_t zero_bytes = off;                 // flags + hcat zeroed per launch
  bf16* xg    = (bf16*)alloc((size_t)2048 * 512 * 2);
  bf16* srcb  = (bf16*)alloc((size_t)2048 * 1024 * 2);
  bf16* fcWb  = (bf16*)alloc((size_t)32000 * 1024 * 2);
  bf16* Wxf   = (bf16*)alloc((size_t)2048 * 512 * 2);
  bf16* Wxb   = (bf16*)alloc((size_t)2048 * 512 * 2);
  bf16* Wrecf = (bf16*)alloc((size_t)2048 * 1024 * 2);
  bf16* Wrecb = (bf16*)alloc((size_t)2048 * 1024 * 2);
  bf16* attWtf = (bf16*)alloc((size_t)512 * 1024 * 2);
  bf16* attWtb = (bf16*)alloc((size_t)512 * 1024 * 2);
  bf16* ahW2f = (bf16*)alloc((size_t)512 * 1024 * 2);
  bf16* ahW2b = (bf16*)alloc((size_t)512 * 1024 * 2);
  bf16* Wh1f  = (bf16*)alloc((size_t)512 * 512 * 2);
  bf16* Wh1b  = (bf16*)alloc((size_t)512 * 512 * 2);
  bf16* Aff   = (bf16*)alloc((size_t)2048 * 512 * 2);
  bf16* Afb   = (bf16*)alloc((size_t)2048 * 512 * 2);
  bf16* Bmf   = (bf16*)alloc((size_t)2048 * 512 * 2);
  bf16* Bmb   = (bf16*)alloc((size_t)2048 * 512 * 2);
  bf16* Bmtf  = (bf16*)alloc((size_t)2048 * 512 * 2);
  bf16* Bmtb  = (bf16*)alloc((size_t)2048 * 512 * 2);
  float* c0f  = (float*)alloc(2048 * 4);
  float* c0b  = (float*)alloc(2048 * 4);
  bf16* hh0   = (bf16*)alloc((size_t)65 * 32 * 512 * 2);
  bf16* hh1   = (bf16*)alloc((size_t)65 * 32 * 512 * 2);
  bf16* hb0   = (bf16*)alloc((size_t)65 * 32 * 512 * 2);
  bf16* hb1   = (bf16*)alloc((size_t)65 * 32 * 512 * 2);
  bf16* Uf    = (bf16*)alloc((size_t)64 * 32 * 512 * 2);
  bf16* Ub    = (bf16*)alloc((size_t)64 * 32 * 512 * 2);
  float* cst0 = (float*)alloc((size_t)512 * 32 * 4);
  float* cst1 = (float*)alloc((size_t)512 * 32 * 4);

  hipMemsetAsync(d_ws, 0, zero_bytes, stream);

  k_xg<<<4096, 256, 0, stream>>>(emb, trg, xg);
  k_srcb<<<8192, 256, 0, stream>>>(src, srcb);
  k_fcw<<<8192, 256, 0, stream>>>(fcW, fcWb);
  k_wpack<<<2048, 256, 0, stream>>>(fWih, fWhh, bWih, bWhh, fattW, battW, bahW, fahW,
                                    Wxf, Wxb, Wrecf, Wrecb, attWtf, attWtb, ahW2f, ahW2b,
                                    Wh1f, Wh1b);
  k_c0<<<2048, 256, 0, stream>>>(src, fattb, battb, c0f, c0b);
  k_init<<<64, 256, 0, stream>>>(feed, hid, hh0, hh1, hb0, hb1, cst0, cst1);

  // A[r][j] = src @ attW ;  Bm[r][o] = src @ ahW_ct^T   (x-projection folded
  // into the scan's Phase A -> no Xp GEMMs)
  gemm_k<bf16, false><<<dim3(4, 16), 256, 0, stream>>>(srcb, attWtf, Aff, nullptr, 2048, 512, 1024);
  gemm_k<bf16, false><<<dim3(4, 16), 256, 0, stream>>>(srcb, attWtb, Afb, nullptr, 2048, 512, 1024);
  gemm_k<bf16, false><<<dim3(4, 16), 256, 0, stream>>>(srcb, ahW2f, Bmf, nullptr, 2048, 512, 1024);
  gemm_k<bf16, false><<<dim3(4, 16), 256, 0, stream>>>(srcb, ahW2b, Bmb, nullptr, 2048, 512, 1024);
  k_bmt<<<4096, 256, 0, stream>>>(Bmf, Bmtf);
  k_bmt<<<4096, 256, 0, stream>>>(Bmb, Bmtb);

  ScanP sp;
  sp.Wrec[0] = Wrecf; sp.Wrec[1] = Wrecb;
  sp.Wx[0] = Wxf;     sp.Wx[1] = Wxb;
  sp.xg = xg;
  sp.Af[0] = Aff;     sp.Af[1] = Afb;
  sp.Bmt[0] = Bmtf;   sp.Bmt[1] = Bmtb;
  sp.Wh1[0] = Wh1f;   sp.Wh1[1] = Wh1b;
  sp.bih[0] = fbih;   sp.bih[1] = bbih;
  sp.bhh[0] = fbhh;   sp.bhh[1] = bbhh;
  sp.c0[0] = c0f;     sp.c0[1] = c0b;
  sp.ahb[0] = bahb;   sp.ahb[1] = fahb;   // att_hidden weights are swapped in the reference
  sp.mask = mask;
  sp.hh[0] = hh0;     sp.hh[1] = hh1;
  sp.hb[0] = hb0;     sp.hb[1] = hb1;
  sp.U[0] = Uf;       sp.U[1] = Ub;
  sp.cst[0] = cst0;   sp.cst[1] = cst1;
  sp.hcat = hcat;     sp.flags = flags;
  scan_k<<<64, 256, 0, stream>>>(sp);

  // logits[b*64+t][v] = hcat @ fcW^T + fcb  (LDS-staged)
  gemm_out<<<4000, 256, 0, stream>>>(hcat, fcWb, (float*)d_out, fcb);
}

// Round 13
// 2611.734 us; speedup vs baseline: 1.4880x; 1.1260x over previous
//
#include <hip/hip_runtime.h>
#include <hip/hip_bf16.h>
#include <math.h>

typedef __hip_bfloat16 bf16;
typedef __attribute__((ext_vector_type(8))) short short8b;
typedef __attribute__((ext_vector_type(8))) __bf16 bf16x8;
typedef __attribute__((ext_vector_type(4))) float f32x4;

#define SCALE_F 0.04419417382415922f  // 1/sqrt(512)

// ---- MFMA wrapper tolerant of either builtin signature (v8i16 or v8bf16) ----
template <typename V>
static __device__ inline auto mfma_try(V a, V b, f32x4 c, int)
    -> decltype(__builtin_amdgcn_mfma_f32_16x16x32_bf16(a, b, c, 0, 0, 0)) {
  return __builtin_amdgcn_mfma_f32_16x16x32_bf16(a, b, c, 0, 0, 0);
}
template <typename V>
static __device__ inline auto mfma_try(V a, V b, f32x4 c, long)
    -> decltype(__builtin_amdgcn_mfma_f32_16x16x32_bf16(
        __builtin_bit_cast(bf16x8, a), __builtin_bit_cast(bf16x8, b), c, 0, 0, 0)) {
  return __builtin_amdgcn_mfma_f32_16x16x32_bf16(
      __builtin_bit_cast(bf16x8, a), __builtin_bit_cast(bf16x8, b), c, 0, 0, 0);
}
static __device__ inline f32x4 MFMA(short8b a, short8b b, f32x4 c) {
  return mfma_try(a, b, c, 0);
}

static __device__ inline short8b ldb8(const bf16* p) {
  return *reinterpret_cast<const short8b*>(p);
}
static __device__ inline float b2f(bf16 v) { return __bfloat162float(v); }
static __device__ inline bf16 f2b(float v) { return __float2bfloat16(v); }
static __device__ inline float s2f(short s) {
  unsigned u = ((unsigned)(unsigned short)s) << 16;
  return __builtin_bit_cast(float, u);
}
static __device__ inline unsigned pack2(float lo, float hi) {
  const unsigned a = (unsigned)__builtin_bit_cast(unsigned short, f2b(lo));
  const unsigned b = (unsigned)__builtin_bit_cast(unsigned short, f2b(hi));
  return a | (b << 16);
}
static __device__ inline float sigm(float x) { return 1.f / (1.f + expf(-x)); }

// write-through stores: bypass L1/L2, land at the LLC (device coherence
// point) -> cross-XCD visible without cache-wide fence ops. (R4-proven.)
static __device__ inline void st2_wt(bf16* p, float v) {
  unsigned ud = (unsigned)__builtin_bit_cast(unsigned short, f2b(v));
  asm volatile("global_store_short %0, %1, off sc0 sc1" ::"v"(p), "v"(ud)
               : "memory");
}
static __device__ inline void st4_wt(bf16* p, float lo, float hi) {
  unsigned ud = pack2(lo, hi);
  asm volatile("global_store_dword %0, %1, off sc0 sc1" ::"v"(p), "v"(ud)
               : "memory");
}

static __device__ inline void st_flag(unsigned* p, unsigned v) {
  asm volatile("global_store_dword %0, %1, off sc0 sc1" ::"v"(p), "v"(v)
               : "memory");
}
static __device__ inline unsigned ld_flag(const unsigned* p) {
  unsigned v;
  asm volatile("global_load_dword %0, %1, off sc0 sc1\n\ts_waitcnt vmcnt(0)"
               : "=v"(v)
               : "v"(p)
               : "memory");
  return v;
}

// ---- contention-free LLC flag barrier (R4-proven) ----
static __device__ inline void gbar(unsigned* flags, unsigned ep, int blk, int tid) {
  asm volatile("s_waitcnt vmcnt(0)" ::: "memory");
  __syncthreads();
  if (tid < 64) {
    unsigned* row = flags + (size_t)ep * 64;
    if (tid == 0) st_flag(row + blk, 1u);
    while (true) {
      const unsigned v = ld_flag(row + tid);
      if (__ballot(v != 0) == ~0ull) break;
      __builtin_amdgcn_s_sleep(1);
    }
  }
  __syncthreads();
}

// =======================  generic MFMA GEMM (prep)  =======================
template <typename OutT, bool HAS_BIAS>
__global__ __launch_bounds__(256) void gemm_k(
    const bf16* __restrict__ A, const bf16* __restrict__ Bw,
    OutT* __restrict__ C, const float* __restrict__ bias,
    int M, int N, int K) {
  const int lane = threadIdx.x & 63;
  const int wid = threadIdx.x >> 6;
  const int m0 = blockIdx.y * 128 + (wid >> 1) * 64;
  const int n0 = blockIdx.x * 128 + (wid & 1) * 64;
  const int lr = lane & 15;
  const int lk = (lane >> 4) * 8;
  f32x4 acc[4][4];
#pragma unroll
  for (int i = 0; i < 4; ++i)
#pragma unroll
    for (int j = 0; j < 4; ++j) acc[i][j] = (f32x4){0.f, 0.f, 0.f, 0.f};
  const bf16* Ap = A + (size_t)(m0 + lr) * K + lk;
  const bf16* Bp = Bw + (size_t)(n0 + lr) * K + lk;
  for (int k0 = 0; k0 < K; k0 += 32) {
    short8b av[4], bv[4];
#pragma unroll
    for (int i = 0; i < 4; ++i) av[i] = ldb8(Ap + (size_t)i * 16 * K + k0);
#pragma unroll
    for (int i = 0; i < 4; ++i) bv[i] = ldb8(Bp + (size_t)i * 16 * K + k0);
#pragma unroll
    for (int mi = 0; mi < 4; ++mi)
#pragma unroll
      for (int ni = 0; ni < 4; ++ni)
        acc[mi][ni] = MFMA(av[mi], bv[ni], acc[mi][ni]);
  }
  const int rb = (lane >> 4) * 4;
#pragma unroll
  for (int mi = 0; mi < 4; ++mi) {
#pragma unroll
    for (int r = 0; r < 4; ++r) {
      const int row = m0 + mi * 16 + rb + r;
#pragma unroll
      for (int ni = 0; ni < 4; ++ni) {
        const int col = n0 + ni * 16 + lr;
        float v = acc[mi][ni][r];
        if (HAS_BIAS) v += bias[col];
        if constexpr (sizeof(OutT) == 2) {
          C[(size_t)row * N + col] = f2b(v);
        } else {
          C[(size_t)row * N + col] = v;
        }
      }
    }
  }
}

// Output GEMM M=2048 N=32000 K=1024, LDS-staged (128x128 tile, BK=32,
// reg-staged global->LDS, 2 barriers/K-step, ds_read_b128 frags). (R11-proven)
__global__ __launch_bounds__(256) void gemm_out(
    const bf16* __restrict__ A, const bf16* __restrict__ Bw,
    float* __restrict__ C, const float* __restrict__ bias) {
  constexpr int K = 1024, N = 32000;
  __shared__ bf16 As[128 * 32];
  __shared__ bf16 Bs[128 * 32];
  const int wgid = blockIdx.x;            // 4000 = 16 m x 250 n, m fastest
  const int mt = wgid & 15, nt = wgid >> 4;
  const int tid = threadIdx.x, lane = tid & 63, wv = tid >> 6;
  const int m0 = mt * 128, n0 = nt * 128;
  const int lr16 = lane & 15, kb = lane >> 4, koff = kb * 8;
  const int r0 = tid >> 2, q0 = tid & 3;
  const int r1 = (tid + 256) >> 2;
  const bf16* Ap0 = A + (size_t)(m0 + r0) * K + q0 * 8;
  const bf16* Ap1 = A + (size_t)(m0 + r1) * K + q0 * 8;
  const bf16* Bp0 = Bw + (size_t)(n0 + r0) * K + q0 * 8;
  const bf16* Bp1 = Bw + (size_t)(n0 + r1) * K + q0 * 8;
  const int wm = (wv >> 1) * 64, wn = (wv & 1) * 64;
  f32x4 acc[4][4];
#pragma unroll
  for (int i = 0; i < 4; ++i)
#pragma unroll
    for (int j = 0; j < 4; ++j) acc[i][j] = (f32x4){0.f, 0.f, 0.f, 0.f};
  short8b a0 = ldb8(Ap0), a1 = ldb8(Ap1), b0 = ldb8(Bp0), b1 = ldb8(Bp1);
  for (int k0 = 0; k0 < K; k0 += 32) {
    __syncthreads();
    *reinterpret_cast<short8b*>(&As[tid * 8]) = a0;
    *reinterpret_cast<short8b*>(&As[(tid + 256) * 8]) = a1;
    *reinterpret_cast<short8b*>(&Bs[tid * 8]) = b0;
    *reinterpret_cast<short8b*>(&Bs[(tid + 256) * 8]) = b1;
    __syncthreads();
    if (k0 + 32 < K) {
      a0 = ldb8(Ap0 + k0 + 32);
      a1 = ldb8(Ap1 + k0 + 32);
      b0 = ldb8(Bp0 + k0 + 32);
      b1 = ldb8(Bp1 + k0 + 32);
    }
    short8b af[4], bfr[4];
#pragma unroll
    for (int i = 0; i < 4; ++i) {
      af[i] = *reinterpret_cast<const short8b*>(&As[(wm + i * 16 + lr16) * 32 + koff]);
      bfr[i] = *reinterpret_cast<const short8b*>(&Bs[(wn + i * 16 + lr16) * 32 + koff]);
    }
#pragma unroll
    for (int mi = 0; mi < 4; ++mi)
#pragma unroll
      for (int ni = 0; ni < 4; ++ni)
        acc[mi][ni] = MFMA(af[mi], bfr[ni], acc[mi][ni]);
  }
#pragma unroll
  for (int mi = 0; mi < 4; ++mi) {
#pragma unroll
    for (int r = 0; r < 4; ++r) {
      const int row = m0 + wm + mi * 16 + kb * 4 + r;
#pragma unroll
      for (int ni = 0; ni < 4; ++ni) {
        const int col = n0 + wn + ni * 16 + lr16;
        C[(size_t)row * N + col] = acc[mi][ni][r] + bias[col];
      }
    }
  }
}

// =======================  prep kernels  =======================
__global__ void k_xg(const float* __restrict__ emb, const int* __restrict__ trg,
                     bf16* __restrict__ xg) {
  const int i = blockIdx.x * 256 + threadIdx.x;   // 2048*512 exact
  const int r = i >> 9, e = i & 511;
  const int t = r >> 5, b = r & 31;
  const int tok = trg[b * 64 + t];
  xg[i] = f2b(emb[(size_t)tok * 512 + e]);
}

__global__ void k_srcb(const float* __restrict__ s, bf16* __restrict__ d) {
  const int i = blockIdx.x * 256 + threadIdx.x;   // 2048*1024 exact
  d[i] = f2b(s[i]);
}

__global__ void k_fcw(const float* __restrict__ s, bf16* __restrict__ d) {
  const size_t stride = (size_t)gridDim.x * blockDim.x;
  for (size_t i = blockIdx.x * (size_t)blockDim.x + threadIdx.x;
       i < (size_t)32000 * 1024; i += stride)
    d[i] = f2b(s[i]);
}

// Bm[b*64+s][o] -> Bmt[b][o][s]  (dense s-contiguous rows for the a2 dot)
__global__ void k_bmt(const bf16* __restrict__ in, bf16* __restrict__ out) {
  const int i = blockIdx.x * 256 + threadIdx.x;   // 32*512*64 = 1048576 exact
  const int b = i >> 15, rem = i & 32767, o = rem >> 6, s = rem & 63;
  out[i] = in[(size_t)(b * 64 + s) * 512 + o];
}

__global__ void k_wpack(const float* __restrict__ fWih, const float* __restrict__ fWhh,
                        const float* __restrict__ bWih, const float* __restrict__ bWhh,
                        const float* __restrict__ fattW, const float* __restrict__ battW,
                        const float* __restrict__ bahW, const float* __restrict__ fahW,
                        bf16* Wxf, bf16* Wxb, bf16* Wrecf, bf16* Wrecb,
                        bf16* attWtf, bf16* attWtb, bf16* ahW2f, bf16* ahW2b,
                        bf16* Wh1f, bf16* Wh1b) {
  const int stride = gridDim.x * blockDim.x;
  const int i0 = blockIdx.x * blockDim.x + threadIdx.x;
  for (int i = i0; i < 2048 * 512; i += stride) {        // Wih x-slice
    const int gc = i >> 9, k = i & 511;
    Wxf[i] = f2b(fWih[(size_t)gc * 1024 + k]);
    Wxb[i] = f2b(bWih[(size_t)gc * 1024 + k]);
  }
  for (int i = i0; i < 2048 * 1024; i += stride) {       // [Wih_h | Whh]
    const int gc = i >> 10, k = i & 1023;
    float vf, vb;
    if (k < 512) { vf = fWih[(size_t)gc * 1024 + 512 + k]; vb = bWih[(size_t)gc * 1024 + 512 + k]; }
    else         { vf = fWhh[(size_t)gc * 512 + k - 512]; vb = bWhh[(size_t)gc * 512 + k - 512]; }
    Wrecf[i] = f2b(vf); Wrecb[i] = f2b(vb);
  }
  for (int i = i0; i < 512 * 1024; i += stride) {        // attW transpose
    const int j = i >> 10, d = i & 1023;
    attWtf[i] = f2b(fattW[(size_t)d * 512 + j]);
    attWtb[i] = f2b(battW[(size_t)d * 512 + j]);
  }
  for (int i = i0; i < 512 * 1024; i += stride) {        // ah_W ct-slice (swapped: fwd uses bah)
    const int o = i >> 10, d = i & 1023;
    ahW2f[i] = f2b(bahW[(size_t)o * 1536 + 512 + d]);
    ahW2b[i] = f2b(fahW[(size_t)o * 1536 + 512 + d]);
  }
  for (int i = i0; i < 512 * 512; i += stride) {         // ah_W h-slice bf16 [o][k]
    const int o = i >> 9, k = i & 511;
    Wh1f[i] = f2b(bahW[(size_t)o * 1536 + k]);
    Wh1b[i] = f2b(fahW[(size_t)o * 1536 + k]);
  }
}

__global__ void k_c0(const float* __restrict__ src, const float* __restrict__ fb,
                     const float* __restrict__ bb, float* __restrict__ c0f,
                     float* __restrict__ c0b) {
  const int r = blockIdx.x;
  const int tid = threadIdx.x;
  float pf = 0.f, pb = 0.f;
  for (int d = tid; d < 1024; d += 256) {
    const float s = src[(size_t)r * 1024 + d];
    pf += s * fb[d];
    pb += s * bb[d];
  }
#pragma unroll
  for (int d = 1; d < 64; d <<= 1) { pf += __shfl_xor(pf, d); pb += __shfl_xor(pb, d); }
  __shared__ float rf[4], rb2[4];
  if ((tid & 63) == 0) { rf[tid >> 6] = pf; rb2[tid >> 6] = pb; }
  __syncthreads();
  if (tid == 0) {
    c0f[r] = (rf[0] + rf[1] + rf[2] + rf[3]) * SCALE_F;
    c0b[r] = (rb2[0] + rb2[1] + rb2[2] + rb2[3]) * SCALE_F;
  }
}

// rolling state buffers per dir: hh[65][32][512], hb[65][32][512] bf16
__global__ void k_init(const float* __restrict__ feed, const float* __restrict__ hid,
                       bf16* hh0, bf16* hh1, bf16* hb0, bf16* hb1,
                       float* cst0, float* cst1) {
  const int i = blockIdx.x * 256 + threadIdx.x;   // 32*512 exact
  const int b = i >> 9, k = i & 511;
  hh0[i] = f2b(feed[k]);
  hh1[i] = f2b(feed[512 + k]);
  hb0[i] = f2b(hid[k]);
  hb1[i] = f2b(hid[1024 + k]);
  cst0[k * 32 + b] = hid[512 + k];
  cst1[k * 32 + b] = hid[1536 + k];
}

// =======================  sequential scan (R8-proven 3-phase)  ================
struct ScanP {
  const bf16* Wrec[2]; const bf16* Xp[2]; const bf16* Af[2]; const bf16* Bmt[2];
  const bf16* Wh1[2]; const float* bih[2]; const float* bhh[2];
  const float* c0[2]; const float* ahb[2]; const float* mask;
  bf16* hh[2]; bf16* hb[2]; bf16* U[2]; float* cst[2]; bf16* hcat; unsigned* flags;
};

__global__ __launch_bounds__(256) void scan_k(ScanP P) {
  const int blk = blockIdx.x;     // 64 blocks
  const int dir = blk >> 5;       // 0 fwd, 1 bwd
  const int g = blk & 31;         // PhaseA/B1: j-slice; PhaseB2/C: batch index
  const int tid = threadIdx.x;
  const int lane = tid & 63;
  const int wv = tid >> 6;

  const bf16* __restrict__ Wrec = P.Wrec[dir];
  const bf16* __restrict__ Xp = P.Xp[dir];
  const bf16* __restrict__ Af = P.Af[dir];
  const bf16* __restrict__ Bmt = P.Bmt[dir];
  const bf16* __restrict__ Wh1 = P.Wh1[dir];
  const float* __restrict__ bihp = P.bih[dir];
  const float* __restrict__ bhhp = P.bhh[dir];
  const float* __restrict__ c0v = P.c0[dir];
  const float* __restrict__ ahbp = P.ahb[dir];
  bf16* __restrict__ hhB = P.hh[dir];
  bf16* __restrict__ hbB = P.hb[dir];
  bf16* __restrict__ Ubuf = P.U[dir];
  float* __restrict__ cst = P.cst[dir];

  __shared__ float gl[4][16][33];
  __shared__ float h_lds[512];
  __shared__ float w_part[2][64];
  __shared__ float p_lds[64];

  unsigned ep = 0;
  const int lr16 = lane & 15;
  const int kb = lane >> 4;
  const int koff = kb * 8;

  // prefetched h_{t-1} A-fragments (rows lr16, lr16+16), registers
  short8b pA0[16], pA1[16];
  {
    const bf16* A0 = hbB + (size_t)lr16 * 512;           // slot 0 = h_{-1}
    const bf16* A1 = hbB + (size_t)(lr16 + 16) * 512;
#pragma unroll
    for (int ks = 0; ks < 16; ++ks) {
      pA0[ks] = ldb8(A0 + ks * 32 + koff);
      pA1[ks] = ldb8(A1 + ks * 32 + koff);
    }
  }

  for (int t = 0; t < 64; ++t) {
    const bf16* hhR = hhB + (size_t)t * 32 * 512;        // hhat_{t-1}
    bf16* hhW = hhB + (size_t)(t + 1) * 32 * 512;
    bf16* hbW = hbB + (size_t)(t + 1) * 32 * 512;        // h_t (written below)

    // ---------- Phase A: gates (MFMA) + LSTM cell, block owns j-slice ----------
    {
      const int gate = wv;                   // wave 0..3 -> i,f,g,o
      const int gc = gate * 512 + g * 16 + lr16;
      const bf16* Brow = Wrec + (size_t)gc * 1024;
      const bf16* A0h = hhR + (size_t)lr16 * 512;
      const bf16* A1h = hhR + (size_t)(lr16 + 16) * 512;
      f32x4 ac0 = (f32x4){0.f, 0.f, 0.f, 0.f};
      f32x4 ac1 = (f32x4){0.f, 0.f, 0.f, 0.f};
#pragma unroll
      for (int ks = 0; ks < 16; ++ks) {      // h part (prefetched regs)
        const int k = ks * 32 + koff;
        const short8b bv = ldb8(Brow + 512 + k);
        ac0 = MFMA(pA0[ks], bv, ac0);
        ac1 = MFMA(pA1[ks], bv, ac1);
      }
      // hhat part: stage loads in 2 chunks of 8 so 16 loads are in flight
#pragma unroll
      for (int c = 0; c < 2; ++c) {
        short8b sa[8], sb[8];
#pragma unroll
        for (int i = 0; i < 8; ++i) {
          const int k = (c * 8 + i) * 32 + koff;
          sa[i] = ldb8(A0h + k);
          sb[i] = ldb8(A1h + k);
        }
#pragma unroll
        for (int i = 0; i < 8; ++i) {
          const int k = (c * 8 + i) * 32 + koff;
          const short8b bv = ldb8(Brow + k);
          ac0 = MFMA(sa[i], bv, ac0);
          ac1 = MFMA(sb[i], bv, ac1);
        }
      }
      const int tcol = dir ? (63 - t) : t;
      const float bsum = bihp[gc] + bhhp[gc];
      const bf16* xpc = Xp + (size_t)gc * 2048 + tcol * 32;
#pragma unroll
      for (int r = 0; r < 4; ++r) {
        const int brow = kb * 4 + r;   // D: row=(lane>>4)*4+reg (batch), col=lane&15 (gc)
        gl[gate][lr16][brow] = ac0[r] + b2f(xpc[brow]) + bsum;
        gl[gate][lr16][brow + 16] = ac1[r] + b2f(xpc[brow + 16]) + bsum;
      }
    }
    __syncthreads();
    {
      const int b = tid & 31;
      const int jp = (tid >> 5) * 2;         // two consecutive j per thread
      float hn2[2];
#pragma unroll
      for (int u = 0; u < 2; ++u) {
        const int jl = jp + u;
        const int j = g * 16 + jl;
        const float gi = gl[0][jl][b];
        const float gf = gl[1][jl][b];
        const float gg = gl[2][jl][b];
        const float go = gl[3][jl][b];
        float cn = sigm(gf) * cst[j * 32 + b] + sigm(gi) * tanhf(gg);
        float hn = sigm(go) * tanhf(cn);
        if (dir) {
          const float m = P.mask[b * 64 + (63 - t)];
          hn *= m; cn *= m;
        }
        cst[j * 32 + b] = cn;                               // block-private
        hn2[u] = hn;
      }
      st4_wt(hbW + (size_t)b * 512 + g * 16 + jp, hn2[0], hn2[1]);
    }
    gbar(P.flags, ep++, blk, tid);

    // ---------- Phase B: U (wave 0, j-slice) + attention (waves 1-3, batch g) ----------
    if (wv == 0) {
      // U[b, o-slice] = Wh1[o-slice,:] . h_t[b,:]   (MFMA, K=512)
      const bf16* Brow = Wh1 + (size_t)(g * 16 + lr16) * 512;
      const bf16* A0 = hbW + (size_t)lr16 * 512;
      const bf16* A1 = hbW + (size_t)(lr16 + 16) * 512;
      f32x4 u0 = (f32x4){0.f, 0.f, 0.f, 0.f};
      f32x4 u1 = (f32x4){0.f, 0.f, 0.f, 0.f};
#pragma unroll
      for (int ks = 0; ks < 16; ++ks) {
        const int k = ks * 32 + koff;
        const short8b bv = ldb8(Brow + k);
        u0 = MFMA(ldb8(A0 + k), bv, u0);
        u1 = MFMA(ldb8(A1 + k), bv, u1);
      }
      bf16* Uw = Ubuf + (size_t)t * 32 * 512;
      const int o = g * 16 + lr16;
#pragma unroll
      for (int r = 0; r < 4; ++r) {
        const int b0 = kb * 4 + r;
        st2_wt(Uw + (size_t)b0 * 512 + o, u0[r]);
        st2_wt(Uw + (size_t)(b0 + 16) * 512 + o, u1[r]);
      }
    } else if (wv == 1) {
      const short8b v = ldb8(hbW + (size_t)g * 512 + lane * 8);  // h_t[g,:] -> LDS
#pragma unroll
      for (int e = 0; e < 8; ++e) h_lds[lane * 8 + e] = s2f(v[e]);
    }
    __syncthreads();
    if (wv == 1 || wv == 2) {
      const int q = wv - 1;
      const bf16* arow = Af + (size_t)(g * 64 + lane) * 512 + q * 256;
      float part = 0.f;
#pragma unroll 8
      for (int k8 = 0; k8 < 256; k8 += 8) {
        const short8b v = ldb8(arow + k8);
#pragma unroll
        for (int e = 0; e < 8; ++e) part += h_lds[q * 256 + k8 + e] * s2f(v[e]);
      }
      w_part[q][lane] = part;
    }
    __syncthreads();
    if (wv == 3) {
      const float v = (w_part[0][lane] + w_part[1][lane]) * SCALE_F + c0v[g * 64 + lane];
      float mx = v;
#pragma unroll
      for (int d = 1; d < 64; d <<= 1) mx = fmaxf(mx, __shfl_xor(mx, d));
      const float e = expf(v - mx);
      float sm = e;
#pragma unroll
      for (int d = 1; d < 64; d <<= 1) sm += __shfl_xor(sm, d);
      p_lds[lane] = e / sm;
    }
    __syncthreads();
    // acc2 = ahb + p . Bm : thread owns o-pair (2*tid, 2*tid+1); Bmt rows are
    // s-contiguous -> 16 dense independent 16B loads, one latency round trip.
    float a2[2];
    {
      const int o2 = tid * 2;
      const bf16* bm0 = Bmt + ((size_t)g * 512 + o2) * 64;
      short8b v0[8], v1[8];
#pragma unroll
      for (int i = 0; i < 8; ++i) {
        v0[i] = ldb8(bm0 + i * 8);
        v1[i] = ldb8(bm0 + 64 + i * 8);
      }
      float s0 = ahbp[o2], s1 = ahbp[o2 + 1];
#pragma unroll
      for (int i = 0; i < 8; ++i)
#pragma unroll
        for (int e = 0; e < 8; ++e) {
          const float p = p_lds[i * 8 + e];
          s0 += p * s2f(v0[i][e]);
          s1 += p * s2f(v1[i][e]);
        }
      a2[0] = s0; a2[1] = s1;
    }
    gbar(P.flags, ep++, blk, tid);

    // ---------- Phase C: hhat = tanh(U + acc2), batch g ----------
    {
      const int o2 = tid * 2;
      const unsigned uu =
          *reinterpret_cast<const unsigned*>(Ubuf + ((size_t)t * 32 + g) * 512 + o2);
      const float h0 = tanhf(a2[0] + s2f((short)(uu & 0xffffu)));
      const float h1 = tanhf(a2[1] + s2f((short)(uu >> 16)));
      st4_wt(hhW + (size_t)g * 512 + o2, h0, h1);
      const unsigned hp = pack2(h0, h1);
      if (dir == 0) {
        *reinterpret_cast<unsigned*>(P.hcat + (size_t)(g * 64 + t) * 1024 + o2) = hp;
      } else if (t >= 2) {
        *reinterpret_cast<unsigned*>(P.hcat + (size_t)(g * 64 + t - 2) * 1024 + 512 + o2) = hp;
      }
      if (t < 63) {                            // prefetch h_t frags for next Phase A
        const bf16* A0 = hbW + (size_t)lr16 * 512;
        const bf16* A1 = hbW + (size_t)(lr16 + 16) * 512;
#pragma unroll
        for (int ks = 0; ks < 16; ++ks) {
          pA0[ks] = ldb8(A0 + ks * 32 + koff);
          pA1[ks] = ldb8(A1 + ks * 32 + koff);
        }
      }
    }
    gbar(P.flags, ep++, blk, tid);
  }
}

// =======================  host  =======================
extern "C" void kernel_launch(void* const* d_in, const int* in_sizes, int n_in,
                              void* d_out, int out_size, void* d_ws, size_t ws_size,
                              hipStream_t stream) {
  (void)in_sizes; (void)n_in; (void)out_size; (void)ws_size;
  const float* src  = (const float*)d_in[0];
  const int*   trg  = (const int*)d_in[1];
  const float* mask = (const float*)d_in[2];
  const float* emb  = (const float*)d_in[3];
  const float* fWih = (const float*)d_in[4];
  const float* fWhh = (const float*)d_in[5];
  const float* fbih = (const float*)d_in[6];
  const float* fbhh = (const float*)d_in[7];
  const float* bWih = (const float*)d_in[8];
  const float* bWhh = (const float*)d_in[9];
  const float* bbih = (const float*)d_in[10];
  const float* bbhh = (const float*)d_in[11];
  const float* fattW = (const float*)d_in[12];
  const float* fattb = (const float*)d_in[13];
  const float* battW = (const float*)d_in[14];
  const float* battb = (const float*)d_in[15];
  const float* fahW = (const float*)d_in[16];
  const float* fahb = (const float*)d_in[17];
  const float* bahW = (const float*)d_in[18];
  const float* bahb = (const float*)d_in[19];
  const float* fcW  = (const float*)d_in[20];
  const float* fcb  = (const float*)d_in[21];
  const float* feed = (const float*)d_in[22];
  const float* hid  = (const float*)d_in[23];

  char* wsp = (char*)d_ws;
  size_t off = 0;
  auto alloc = [&](size_t bytes) -> void* {
    void* p = wsp + off;
    off += (bytes + 255) & ~(size_t)255;
    return p;
  };
  unsigned* flags = (unsigned*)alloc((size_t)192 * 64 * 4);
  bf16* hcat = (bf16*)alloc((size_t)2048 * 1024 * 2);
  const size_t zero_bytes = off;                 // flags + hcat zeroed per launch
  bf16* xg    = (bf16*)alloc((size_t)2048 * 512 * 2);
  bf16* srcb  = (bf16*)alloc((size_t)2048 * 1024 * 2);
  bf16* fcWb  = (bf16*)alloc((size_t)32000 * 1024 * 2);
  bf16* Wxf   = (bf16*)alloc((size_t)2048 * 512 * 2);
  bf16* Wxb   = (bf16*)alloc((size_t)2048 * 512 * 2);
  bf16* Wrecf = (bf16*)alloc((size_t)2048 * 1024 * 2);
  bf16* Wrecb = (bf16*)alloc((size_t)2048 * 1024 * 2);
  bf16* attWtf = (bf16*)alloc((size_t)512 * 1024 * 2);
  bf16* attWtb = (bf16*)alloc((size_t)512 * 1024 * 2);
  bf16* ahW2f = (bf16*)alloc((size_t)512 * 1024 * 2);
  bf16* ahW2b = (bf16*)alloc((size_t)512 * 1024 * 2);
  bf16* Wh1f  = (bf16*)alloc((size_t)512 * 512 * 2);
  bf16* Wh1b  = (bf16*)alloc((size_t)512 * 512 * 2);
  bf16* Xpf   = (bf16*)alloc((size_t)2048 * 2048 * 2);
  bf16* Xpb   = (bf16*)alloc((size_t)2048 * 2048 * 2);
  bf16* Aff   = (bf16*)alloc((size_t)2048 * 512 * 2);
  bf16* Afb   = (bf16*)alloc((size_t)2048 * 512 * 2);
  bf16* Bmf   = (bf16*)alloc((size_t)2048 * 512 * 2);
  bf16* Bmb   = (bf16*)alloc((size_t)2048 * 512 * 2);
  bf16* Bmtf  = (bf16*)alloc((size_t)2048 * 512 * 2);
  bf16* Bmtb  = (bf16*)alloc((size_t)2048 * 512 * 2);
  float* c0f  = (float*)alloc(2048 * 4);
  float* c0b  = (float*)alloc(2048 * 4);
  bf16* hh0   = (bf16*)alloc((size_t)65 * 32 * 512 * 2);
  bf16* hh1   = (bf16*)alloc((size_t)65 * 32 * 512 * 2);
  bf16* hb0   = (bf16*)alloc((size_t)65 * 32 * 512 * 2);
  bf16* hb1   = (bf16*)alloc((size_t)65 * 32 * 512 * 2);
  bf16* Uf    = (bf16*)alloc((size_t)64 * 32 * 512 * 2);
  bf16* Ub    = (bf16*)alloc((size_t)64 * 32 * 512 * 2);
  float* cst0 = (float*)alloc((size_t)512 * 32 * 4);
  float* cst1 = (float*)alloc((size_t)512 * 32 * 4);

  hipMemsetAsync(d_ws, 0, zero_bytes, stream);

  k_xg<<<4096, 256, 0, stream>>>(emb, trg, xg);
  k_srcb<<<8192, 256, 0, stream>>>(src, srcb);
  k_fcw<<<8192, 256, 0, stream>>>(fcW, fcWb);
  k_wpack<<<2048, 256, 0, stream>>>(fWih, fWhh, bWih, bWhh, fattW, battW, bahW, fahW,
                                    Wxf, Wxb, Wrecf, Wrecb, attWtf, attWtb, ahW2f, ahW2b,
                                    Wh1f, Wh1b);
  k_c0<<<2048, 256, 0, stream>>>(src, fattb, battb, c0f, c0b);
  k_init<<<64, 256, 0, stream>>>(feed, hid, hh0, hh1, hb0, hb1, cst0, cst1);

  // Xp[gc][r] = (x @ Wih_x^T)^T  (gc-major so scan reads are b-coalesced)
  gemm_k<bf16, false><<<dim3(16, 16), 256, 0, stream>>>(Wxf, xg, Xpf, nullptr, 2048, 2048, 512);
  gemm_k<bf16, false><<<dim3(16, 16), 256, 0, stream>>>(Wxb, xg, Xpb, nullptr, 2048, 2048, 512);
  // A[r][j] = src @ attW ;  Bm[r][o] = src @ ahW_ct^T
  gemm_k<bf16, false><<<dim3(4, 16), 256, 0, stream>>>(srcb, attWtf, Aff, nullptr, 2048, 512, 1024);
  gemm_k<bf16, false><<<dim3(4, 16), 256, 0, stream>>>(srcb, attWtb, Afb, nullptr, 2048, 512, 1024);
  gemm_k<bf16, false><<<dim3(4, 16), 256, 0, stream>>>(srcb, ahW2f, Bmf, nullptr, 2048, 512, 1024);
  gemm_k<bf16, false><<<dim3(4, 16), 256, 0, stream>>>(srcb, ahW2b, Bmb, nullptr, 2048, 512, 1024);
  k_bmt<<<4096, 256, 0, stream>>>(Bmf, Bmtf);
  k_bmt<<<4096, 256, 0, stream>>>(Bmb, Bmtb);

  ScanP sp;
  sp.Wrec[0] = Wrecf; sp.Wrec[1] = Wrecb;
  sp.Xp[0] = Xpf;     sp.Xp[1] = Xpb;
  sp.Af[0] = Aff;     sp.Af[1] = Afb;
  sp.Bmt[0] = Bmtf;   sp.Bmt[1] = Bmtb;
  sp.Wh1[0] = Wh1f;   sp.Wh1[1] = Wh1b;
  sp.bih[0] = fbih;   sp.bih[1] = bbih;
  sp.bhh[0] = fbhh;   sp.bhh[1] = bbhh;
  sp.c0[0] = c0f;     sp.c0[1] = c0b;
  sp.ahb[0] = bahb;   sp.ahb[1] = fahb;   // att_hidden weights are swapped in the reference
  sp.mask = mask;
  sp.hh[0] = hh0;     sp.hh[1] = hh1;
  sp.hb[0] = hb0;     sp.hb[1] = hb1;
  sp.U[0] = Uf;       sp.U[1] = Ub;
  sp.cst[0] = cst0;   sp.cst[1] = cst1;
  sp.hcat = hcat;     sp.flags = flags;
  scan_k<<<64, 256, 0, stream>>>(sp);

  // logits[b*64+t][v] = hcat @ fcW^T + fcb  (LDS-staged)
  gemm_out<<<4000, 256, 0, stream>>>(hcat, fcWb, (float*)d_out, fcb);
}

// Round 14
// 2377.691 us; speedup vs baseline: 1.6344x; 1.0984x over previous
//
#include <hip/hip_runtime.h>
#include <hip/hip_bf16.h>
#include <math.h>

typedef __hip_bfloat16 bf16;
typedef __attribute__((ext_vector_type(8))) short short8b;
typedef __attribute__((ext_vector_type(8))) __bf16 bf16x8;
typedef __attribute__((ext_vector_type(4))) float f32x4;
typedef __attribute__((ext_vector_type(2))) unsigned u32x2;

#define SCALE_F 0.04419417382415922f  // 1/sqrt(512)

// ---- MFMA wrapper tolerant of either builtin signature (v8i16 or v8bf16) ----
template <typename V>
static __device__ inline auto mfma_try(V a, V b, f32x4 c, int)
    -> decltype(__builtin_amdgcn_mfma_f32_16x16x32_bf16(a, b, c, 0, 0, 0)) {
  return __builtin_amdgcn_mfma_f32_16x16x32_bf16(a, b, c, 0, 0, 0);
}
template <typename V>
static __device__ inline auto mfma_try(V a, V b, f32x4 c, long)
    -> decltype(__builtin_amdgcn_mfma_f32_16x16x32_bf16(
        __builtin_bit_cast(bf16x8, a), __builtin_bit_cast(bf16x8, b), c, 0, 0, 0)) {
  return __builtin_amdgcn_mfma_f32_16x16x32_bf16(
      __builtin_bit_cast(bf16x8, a), __builtin_bit_cast(bf16x8, b), c, 0, 0, 0);
}
static __device__ inline f32x4 MFMA(short8b a, short8b b, f32x4 c) {
  return mfma_try(a, b, c, 0);
}

static __device__ inline short8b ldb8(const bf16* p) {
  return *reinterpret_cast<const short8b*>(p);
}
static __device__ inline float b2f(bf16 v) { return __bfloat162float(v); }
static __device__ inline bf16 f2b(float v) { return __float2bfloat16(v); }
static __device__ inline float s2f(short s) {
  unsigned u = ((unsigned)(unsigned short)s) << 16;
  return __builtin_bit_cast(float, u);
}
static __device__ inline unsigned pack2(float lo, float hi) {
  const unsigned a = (unsigned)__builtin_bit_cast(unsigned short, f2b(lo));
  const unsigned b = (unsigned)__builtin_bit_cast(unsigned short, f2b(hi));
  return a | (b << 16);
}
static __device__ inline float sigm(float x) { return 1.f / (1.f + expf(-x)); }

// write-through stores: bypass L1/L2, land at the LLC (device coherence
// point) -> cross-XCD visible without cache-wide fence ops. (R4-proven.)
static __device__ inline void st4_wt(bf16* p, float lo, float hi) {
  unsigned ud = pack2(lo, hi);
  asm volatile("global_store_dword %0, %1, off sc0 sc1" ::"v"(p), "v"(ud)
               : "memory");
}
// packed 4-bf16 (8B) WT store: adjacent lanes fill whole sectors -> no
// write amplification (the R11 failure root cause, fixed).
static __device__ inline void st8_wt(bf16* p, f32x4 v) {
  u32x2 ud;
  ud[0] = pack2(v[0], v[1]);
  ud[1] = pack2(v[2], v[3]);
  asm volatile("global_store_dwordx2 %0, %1, off sc0 sc1" ::"v"(p), "v"(ud)
               : "memory");
}

static __device__ inline void st_flag(unsigned* p, unsigned v) {
  asm volatile("global_store_dword %0, %1, off sc0 sc1" ::"v"(p), "v"(v)
               : "memory");
}
static __device__ inline unsigned ld_flag(const unsigned* p) {
  unsigned v;
  asm volatile("global_load_dword %0, %1, off sc0 sc1\n\ts_waitcnt vmcnt(0)"
               : "=v"(v)
               : "v"(p)
               : "memory");
  return v;
}

// batched LLC-direct dword loads (no internal wait -> caller overlaps+drains)
static __device__ inline void ld8_dw(
    const unsigned* p0, const unsigned* p1, const unsigned* p2, const unsigned* p3,
    const unsigned* p4, const unsigned* p5, const unsigned* p6, const unsigned* p7,
    unsigned& o0, unsigned& o1, unsigned& o2, unsigned& o3,
    unsigned& o4, unsigned& o5, unsigned& o6, unsigned& o7) {
  asm volatile(
      "global_load_dword %0, %8, off sc0 sc1\n\t"
      "global_load_dword %1, %9, off sc0 sc1\n\t"
      "global_load_dword %2, %10, off sc0 sc1\n\t"
      "global_load_dword %3, %11, off sc0 sc1\n\t"
      "global_load_dword %4, %12, off sc0 sc1\n\t"
      "global_load_dword %5, %13, off sc0 sc1\n\t"
      "global_load_dword %6, %14, off sc0 sc1\n\t"
      "global_load_dword %7, %15, off sc0 sc1"
      : "=&v"(o0), "=&v"(o1), "=&v"(o2), "=&v"(o3),
        "=&v"(o4), "=&v"(o5), "=&v"(o6), "=&v"(o7)
      : "v"(p0), "v"(p1), "v"(p2), "v"(p3), "v"(p4), "v"(p5), "v"(p6), "v"(p7)
      : "memory");
}

// ---- contention-free LLC flag barrier (R4-proven) ----
static __device__ inline void gbar(unsigned* flags, unsigned ep, int blk, int tid) {
  asm volatile("s_waitcnt vmcnt(0)" ::: "memory");
  __syncthreads();
  if (tid < 64) {
    unsigned* row = flags + (size_t)ep * 64;
    if (tid == 0) st_flag(row + blk, 1u);
    while (true) {
      const unsigned v = ld_flag(row + tid);
      if (__ballot(v != 0) == ~0ull) break;
      __builtin_amdgcn_s_sleep(1);
    }
  }
  __syncthreads();
}

// =======================  generic MFMA GEMM (prep)  =======================
template <typename OutT, bool HAS_BIAS>
__global__ __launch_bounds__(256) void gemm_k(
    const bf16* __restrict__ A, const bf16* __restrict__ Bw,
    OutT* __restrict__ C, const float* __restrict__ bias,
    int M, int N, int K) {
  const int lane = threadIdx.x & 63;
  const int wid = threadIdx.x >> 6;
  const int m0 = blockIdx.y * 128 + (wid >> 1) * 64;
  const int n0 = blockIdx.x * 128 + (wid & 1) * 64;
  const int lr = lane & 15;
  const int lk = (lane >> 4) * 8;
  f32x4 acc[4][4];
#pragma unroll
  for (int i = 0; i < 4; ++i)
#pragma unroll
    for (int j = 0; j < 4; ++j) acc[i][j] = (f32x4){0.f, 0.f, 0.f, 0.f};
  const bf16* Ap = A + (size_t)(m0 + lr) * K + lk;
  const bf16* Bp = Bw + (size_t)(n0 + lr) * K + lk;
  for (int k0 = 0; k0 < K; k0 += 32) {
    short8b av[4], bv[4];
#pragma unroll
    for (int i = 0; i < 4; ++i) av[i] = ldb8(Ap + (size_t)i * 16 * K + k0);
#pragma unroll
    for (int i = 0; i < 4; ++i) bv[i] = ldb8(Bp + (size_t)i * 16 * K + k0);
#pragma unroll
    for (int mi = 0; mi < 4; ++mi)
#pragma unroll
      for (int ni = 0; ni < 4; ++ni)
        acc[mi][ni] = MFMA(av[mi], bv[ni], acc[mi][ni]);
  }
  const int rb = (lane >> 4) * 4;
#pragma unroll
  for (int mi = 0; mi < 4; ++mi) {
#pragma unroll
    for (int r = 0; r < 4; ++r) {
      const int row = m0 + mi * 16 + rb + r;
#pragma unroll
      for (int ni = 0; ni < 4; ++ni) {
        const int col = n0 + ni * 16 + lr;
        float v = acc[mi][ni][r];
        if (HAS_BIAS) v += bias[col];
        if constexpr (sizeof(OutT) == 2) {
          C[(size_t)row * N + col] = f2b(v);
        } else {
          C[(size_t)row * N + col] = v;
        }
      }
    }
  }
}

// Output GEMM M=2048 N=32000 K=1024, LDS-staged. (R11-proven)
__global__ __launch_bounds__(256) void gemm_out(
    const bf16* __restrict__ A, const bf16* __restrict__ Bw,
    float* __restrict__ C, const float* __restrict__ bias) {
  constexpr int K = 1024, N = 32000;
  __shared__ bf16 As[128 * 32];
  __shared__ bf16 Bs[128 * 32];
  const int wgid = blockIdx.x;            // 4000 = 16 m x 250 n, m fastest
  const int mt = wgid & 15, nt = wgid >> 4;
  const int tid = threadIdx.x, lane = tid & 63, wv = tid >> 6;
  const int m0 = mt * 128, n0 = nt * 128;
  const int lr16 = lane & 15, kb = lane >> 4, koff = kb * 8;
  const int r0 = tid >> 2, q0 = tid & 3;
  const int r1 = (tid + 256) >> 2;
  const bf16* Ap0 = A + (size_t)(m0 + r0) * K + q0 * 8;
  const bf16* Ap1 = A + (size_t)(m0 + r1) * K + q0 * 8;
  const bf16* Bp0 = Bw + (size_t)(n0 + r0) * K + q0 * 8;
  const bf16* Bp1 = Bw + (size_t)(n0 + r1) * K + q0 * 8;
  const int wm = (wv >> 1) * 64, wn = (wv & 1) * 64;
  f32x4 acc[4][4];
#pragma unroll
  for (int i = 0; i < 4; ++i)
#pragma unroll
    for (int j = 0; j < 4; ++j) acc[i][j] = (f32x4){0.f, 0.f, 0.f, 0.f};
  short8b a0 = ldb8(Ap0), a1 = ldb8(Ap1), b0 = ldb8(Bp0), b1 = ldb8(Bp1);
  for (int k0 = 0; k0 < K; k0 += 32) {
    __syncthreads();
    *reinterpret_cast<short8b*>(&As[tid * 8]) = a0;
    *reinterpret_cast<short8b*>(&As[(tid + 256) * 8]) = a1;
    *reinterpret_cast<short8b*>(&Bs[tid * 8]) = b0;
    *reinterpret_cast<short8b*>(&Bs[(tid + 256) * 8]) = b1;
    __syncthreads();
    if (k0 + 32 < K) {
      a0 = ldb8(Ap0 + k0 + 32);
      a1 = ldb8(Ap1 + k0 + 32);
      b0 = ldb8(Bp0 + k0 + 32);
      b1 = ldb8(Bp1 + k0 + 32);
    }
    short8b af[4], bfr[4];
#pragma unroll
    for (int i = 0; i < 4; ++i) {
      af[i] = *reinterpret_cast<const short8b*>(&As[(wm + i * 16 + lr16) * 32 + koff]);
      bfr[i] = *reinterpret_cast<const short8b*>(&Bs[(wn + i * 16 + lr16) * 32 + koff]);
    }
#pragma unroll
    for (int mi = 0; mi < 4; ++mi)
#pragma unroll
      for (int ni = 0; ni < 4; ++ni)
        acc[mi][ni] = MFMA(af[mi], bfr[ni], acc[mi][ni]);
  }
#pragma unroll
  for (int mi = 0; mi < 4; ++mi) {
#pragma unroll
    for (int r = 0; r < 4; ++r) {
      const int row = m0 + wm + mi * 16 + kb * 4 + r;
#pragma unroll
      for (int ni = 0; ni < 4; ++ni) {
        const int col = n0 + wn + ni * 16 + lr16;
        C[(size_t)row * N + col] = acc[mi][ni][r] + bias[col];
      }
    }
  }
}

// =======================  prep kernels  =======================
__global__ void k_xg(const float* __restrict__ emb, const int* __restrict__ trg,
                     bf16* __restrict__ xg) {
  const int i = blockIdx.x * 256 + threadIdx.x;   // 2048*512 exact
  const int r = i >> 9, e = i & 511;
  const int t = r >> 5, b = r & 31;
  const int tok = trg[b * 64 + t];
  xg[i] = f2b(emb[(size_t)tok * 512 + e]);
}

__global__ void k_srcb(const float* __restrict__ s, bf16* __restrict__ d) {
  const int i = blockIdx.x * 256 + threadIdx.x;   // 2048*1024 exact
  d[i] = f2b(s[i]);
}

__global__ void k_fcw(const float* __restrict__ s, bf16* __restrict__ d) {
  const size_t stride = (size_t)gridDim.x * blockDim.x;
  for (size_t i = blockIdx.x * (size_t)blockDim.x + threadIdx.x;
       i < (size_t)32000 * 1024; i += stride)
    d[i] = f2b(s[i]);
}

// Bm[b*64+s][o] -> Bmt[b][o][s]  (dense s-contiguous rows for the a2 dot)
__global__ void k_bmt(const bf16* __restrict__ in, bf16* __restrict__ out) {
  const int i = blockIdx.x * 256 + threadIdx.x;   // 32*512*64 = 1048576 exact
  const int b = i >> 15, rem = i & 32767, o = rem >> 6, s = rem & 63;
  out[i] = in[(size_t)(b * 64 + s) * 512 + o];
}

__global__ void k_wpack(const float* __restrict__ fWih, const float* __restrict__ fWhh,
                        const float* __restrict__ bWih, const float* __restrict__ bWhh,
                        const float* __restrict__ fattW, const float* __restrict__ battW,
                        const float* __restrict__ bahW, const float* __restrict__ fahW,
                        bf16* Wxf, bf16* Wxb, bf16* Wrecf, bf16* Wrecb,
                        bf16* attWtf, bf16* attWtb, bf16* ahW2f, bf16* ahW2b,
                        bf16* Wh1f, bf16* Wh1b) {
  const int stride = gridDim.x * blockDim.x;
  const int i0 = blockIdx.x * blockDim.x + threadIdx.x;
  for (int i = i0; i < 2048 * 512; i += stride) {        // Wih x-slice
    const int gc = i >> 9, k = i & 511;
    Wxf[i] = f2b(fWih[(size_t)gc * 1024 + k]);
    Wxb[i] = f2b(bWih[(size_t)gc * 1024 + k]);
  }
  for (int i = i0; i < 2048 * 1024; i += stride) {       // [Wih_h | Whh]
    const int gc = i >> 10, k = i & 1023;
    float vf, vb;
    if (k < 512) { vf = fWih[(size_t)gc * 1024 + 512 + k]; vb = bWih[(size_t)gc * 1024 + 512 + k]; }
    else         { vf = fWhh[(size_t)gc * 512 + k - 512]; vb = bWhh[(size_t)gc * 512 + k - 512]; }
    Wrecf[i] = f2b(vf); Wrecb[i] = f2b(vb);
  }
  for (int i = i0; i < 512 * 1024; i += stride) {        // attW transpose
    const int j = i >> 10, d = i & 1023;
    attWtf[i] = f2b(fattW[(size_t)d * 512 + j]);
    attWtb[i] = f2b(battW[(size_t)d * 512 + j]);
  }
  for (int i = i0; i < 512 * 1024; i += stride) {        // ah_W ct-slice (swapped: fwd uses bah)
    const int o = i >> 10, d = i & 1023;
    ahW2f[i] = f2b(bahW[(size_t)o * 1536 + 512 + d]);
    ahW2b[i] = f2b(fahW[(size_t)o * 1536 + 512 + d]);
  }
  for (int i = i0; i < 512 * 512; i += stride) {         // ah_W h-slice bf16 [o][k]
    const int o = i >> 9, k = i & 511;
    Wh1f[i] = f2b(bahW[(size_t)o * 1536 + k]);
    Wh1b[i] = f2b(fahW[(size_t)o * 1536 + k]);
  }
}

__global__ void k_c0(const float* __restrict__ src, const float* __restrict__ fb,
                     const float* __restrict__ bb, float* __restrict__ c0f,
                     float* __restrict__ c0b) {
  const int r = blockIdx.x;
  const int tid = threadIdx.x;
  float pf = 0.f, pb = 0.f;
  for (int d = tid; d < 1024; d += 256) {
    const float s = src[(size_t)r * 1024 + d];
    pf += s * fb[d];
    pb += s * bb[d];
  }
#pragma unroll
  for (int d = 1; d < 64; d <<= 1) { pf += __shfl_xor(pf, d); pb += __shfl_xor(pb, d); }
  __shared__ float rf[4], rb2[4];
  if ((tid & 63) == 0) { rf[tid >> 6] = pf; rb2[tid >> 6] = pb; }
  __syncthreads();
  if (tid == 0) {
    c0f[r] = (rf[0] + rf[1] + rf[2] + rf[3]) * SCALE_F;
    c0b[r] = (rb2[0] + rb2[1] + rb2[2] + rb2[3]) * SCALE_F;
  }
}

// rolling state buffers per dir: hh[65][32][512], hb[65][32][512] bf16
__global__ void k_init(const float* __restrict__ feed, const float* __restrict__ hid,
                       bf16* hh0, bf16* hh1, bf16* hb0, bf16* hb1,
                       float* cst0, float* cst1) {
  const int i = blockIdx.x * 256 + threadIdx.x;   // 32*512 exact
  const int b = i >> 9, k = i & 511;
  hh0[i] = f2b(feed[k]);
  hh1[i] = f2b(feed[512 + k]);
  hb0[i] = f2b(hid[k]);
  hb1[i] = f2b(hid[1024 + k]);
  cst0[k * 32 + b] = hid[512 + k];
  cst1[k * 32 + b] = hid[1536 + k];
}

// =======================  sequential scan (2 barriers/step)  ==================
// Phase A (block g = j-slice): gates MFMA + cell + h WT + U-PARTIALS
//   Up[g][b][o] = Wh1[o, jslice g] . h_t[b, jslice g]  (contiguous 32KB slab)
// Phase B (block g = batch): attention + softmax + a2 + U-sum + hhat.
struct ScanP {
  const bf16* Wrec[2]; const bf16* Xp[2]; const bf16* Af[2]; const bf16* Bmt[2];
  const bf16* Wh1[2]; const float* bih[2]; const float* bhh[2];
  const float* c0[2]; const float* ahb[2]; const float* mask;
  bf16* hh[2]; bf16* hb[2]; bf16* Up[2]; float* cst[2]; bf16* hcat; unsigned* flags;
};

__global__ __launch_bounds__(256) void scan_k(ScanP P) {
  const int blk = blockIdx.x;     // 64 blocks
  const int dir = blk >> 5;       // 0 fwd, 1 bwd
  const int g = blk & 31;         // PhaseA: j-slice; PhaseB: batch index
  const int tid = threadIdx.x;
  const int lane = tid & 63;
  const int wv = tid >> 6;

  const bf16* __restrict__ Wrec = P.Wrec[dir];
  const bf16* __restrict__ Xp = P.Xp[dir];
  const bf16* __restrict__ Af = P.Af[dir];
  const bf16* __restrict__ Bmt = P.Bmt[dir];
  const bf16* __restrict__ Wh1 = P.Wh1[dir];
  const float* __restrict__ bihp = P.bih[dir];
  const float* __restrict__ bhhp = P.bhh[dir];
  const float* __restrict__ c0v = P.c0[dir];
  const float* __restrict__ ahbp = P.ahb[dir];
  bf16* __restrict__ hhB = P.hh[dir];
  bf16* __restrict__ hbB = P.hb[dir];
  bf16* __restrict__ Up = P.Up[dir];
  float* __restrict__ cst = P.cst[dir];

  __shared__ float gl[4][16][33];
  __shared__ bf16 hs[32][16];           // this block's h j-slice (U partials)
  __shared__ float h_lds[512];
  __shared__ float w_part[4][64];
  __shared__ float p_lds[64];

  unsigned ep = 0;
  const int lr16 = lane & 15;
  const int kb = lane >> 4;
  const int koff = kb * 8;

  // prefetched h_{t-1} A-fragments (rows lr16, lr16+16), registers
  short8b pA0[16], pA1[16];
  {
    const bf16* A0 = hbB + (size_t)lr16 * 512;           // slot 0 = h_{-1}
    const bf16* A1 = hbB + (size_t)(lr16 + 16) * 512;
#pragma unroll
    for (int ks = 0; ks < 16; ++ks) {
      pA0[ks] = ldb8(A0 + ks * 32 + koff);
      pA1[ks] = ldb8(A1 + ks * 32 + koff);
    }
  }

  for (int t = 0; t < 64; ++t) {
    const bf16* hhR = hhB + (size_t)t * 32 * 512;        // hhat_{t-1}
    bf16* hhW = hhB + (size_t)(t + 1) * 32 * 512;
    bf16* hbW = hbB + (size_t)(t + 1) * 32 * 512;        // h_t (written below)

    // ---------- Phase A: gates (MFMA) + LSTM cell + U-partials ----------
    {
      const int gate = wv;                   // wave 0..3 -> i,f,g,o
      const int gc = gate * 512 + g * 16 + lr16;
      const bf16* Brow = Wrec + (size_t)gc * 1024;
      const bf16* A0h = hhR + (size_t)lr16 * 512;
      const bf16* A1h = hhR + (size_t)(lr16 + 16) * 512;
      f32x4 ac0 = (f32x4){0.f, 0.f, 0.f, 0.f};
      f32x4 ac1 = (f32x4){0.f, 0.f, 0.f, 0.f};
#pragma unroll
      for (int ks = 0; ks < 16; ++ks) {      // h part (prefetched regs)
        const int k = ks * 32 + koff;
        const short8b bv = ldb8(Brow + 512 + k);
        ac0 = MFMA(pA0[ks], bv, ac0);
        ac1 = MFMA(pA1[ks], bv, ac1);
      }
#pragma unroll
      for (int c = 0; c < 2; ++c) {          // hhat part, staged 8-deep
        short8b sa[8], sb[8];
#pragma unroll
        for (int i = 0; i < 8; ++i) {
          const int k = (c * 8 + i) * 32 + koff;
          sa[i] = ldb8(A0h + k);
          sb[i] = ldb8(A1h + k);
        }
#pragma unroll
        for (int i = 0; i < 8; ++i) {
          const int k = (c * 8 + i) * 32 + koff;
          const short8b bv = ldb8(Brow + k);
          ac0 = MFMA(sa[i], bv, ac0);
          ac1 = MFMA(sb[i], bv, ac1);
        }
      }
      const int tcol = dir ? (63 - t) : t;
      const float bsum = bihp[gc] + bhhp[gc];
      const bf16* xpc = Xp + (size_t)gc * 2048 + tcol * 32;
#pragma unroll
      for (int r = 0; r < 4; ++r) {
        const int brow = kb * 4 + r;   // D: row=(lane>>4)*4+reg (batch), col=lane&15 (gc)
        gl[gate][lr16][brow] = ac0[r] + b2f(xpc[brow]) + bsum;
        gl[gate][lr16][brow + 16] = ac1[r] + b2f(xpc[brow + 16]) + bsum;
      }
    }
    __syncthreads();
    {
      const int b = tid & 31;
      const int jp = (tid >> 5) * 2;         // two consecutive j per thread
      float hn2[2];
#pragma unroll
      for (int u = 0; u < 2; ++u) {
        const int jl = jp + u;
        const int j = g * 16 + jl;
        const float gi = gl[0][jl][b];
        const float gf = gl[1][jl][b];
        const float gg = gl[2][jl][b];
        const float go = gl[3][jl][b];
        float cn = sigm(gf) * cst[j * 32 + b] + sigm(gi) * tanhf(gg);
        float hn = sigm(go) * tanhf(cn);
        if (dir) {
          const float m = P.mask[b * 64 + (63 - t)];
          hn *= m; cn *= m;
        }
        cst[j * 32 + b] = cn;                               // block-private
        hn2[u] = hn;
      }
      st4_wt(hbW + (size_t)b * 512 + g * 16 + jp, hn2[0], hn2[1]);
      *reinterpret_cast<unsigned*>(&hs[b][jp]) = pack2(hn2[0], hn2[1]);
    }
    __syncthreads();
    {
      // U-partials: Up[g][b][o] = Wh1[o, g*16..+16] . hs[b][:]  (K=16 padded;
      // math verified in R11 -- only the store layout/width changed)
      short8b hx0 = {0, 0, 0, 0, 0, 0, 0, 0};
      short8b hx1 = {0, 0, 0, 0, 0, 0, 0, 0};
      if (kb < 2) {
        hx0 = *reinterpret_cast<const short8b*>(&hs[lr16][kb * 8]);
        hx1 = *reinterpret_cast<const short8b*>(&hs[lr16 + 16][kb * 8]);
      }
      const f32x4 zac = (f32x4){0.f, 0.f, 0.f, 0.f};
      bf16* Ug = Up + (size_t)g * 32 * 512;      // contiguous 32KB slab
#pragma unroll
      for (int oi = 0; oi < 8; ++oi) {
        const int og = wv + oi * 4;              // waves cover og 0..31
        short8b yv = {0, 0, 0, 0, 0, 0, 0, 0};
        if (kb < 2)
          yv = ldb8(Wh1 + (size_t)(og * 16 + lr16) * 512 + g * 16 + kb * 8);
        const f32x4 u0 = MFMA(yv, hx0, zac);     // D[row=o-in-grp, col=b]
        const f32x4 u1 = MFMA(yv, hx1, zac);
        const int oo = og * 16 + kb * 4;
        st8_wt(Ug + (size_t)lr16 * 512 + oo, u0);
        st8_wt(Ug + (size_t)(lr16 + 16) * 512 + oo, u1);
      }
    }
    gbar(P.flags, ep++, blk, tid);

    // ---------- Phase B: attention + a2 + U-sum + hhat, batch g ----------
    if (tid < 64) {
      const short8b v = ldb8(hbW + (size_t)g * 512 + tid * 8);  // h_t[g,:] -> LDS
#pragma unroll
      for (int e = 0; e < 8; ++e) h_lds[tid * 8 + e] = s2f(v[e]);
    }
    __syncthreads();
    {
      // attention dots: wave q covers k in [128q, 128q+128) for all 64 s-rows
      const int q = wv;
      const bf16* arow = Af + (size_t)(g * 64 + lane) * 512 + q * 128;
      float part = 0.f;
#pragma unroll 8
      for (int k8 = 0; k8 < 128; k8 += 8) {
        const short8b v = ldb8(arow + k8);
#pragma unroll
        for (int e = 0; e < 8; ++e) part += h_lds[q * 128 + k8 + e] * s2f(v[e]);
      }
      w_part[q][lane] = part;
    }
    __syncthreads();
    if (wv == 3) {
      const float v = (w_part[0][lane] + w_part[1][lane] + w_part[2][lane] +
                       w_part[3][lane]) * SCALE_F + c0v[g * 64 + lane];
      float mx = v;
#pragma unroll
      for (int d = 1; d < 64; d <<= 1) mx = fmaxf(mx, __shfl_xor(mx, d));
      const float e = expf(v - mx);
      float sm = e;
#pragma unroll
      for (int d = 1; d < 64; d <<= 1) sm += __shfl_xor(sm, d);
      p_lds[lane] = e / sm;
    }
    __syncthreads();
    {
      const int o2 = tid * 2;
      // issue U-partial loads first (LLC-direct); latency hides under a2.
      // dword addr for slab gp: base + gp*8192 (32KB slabs)
      const unsigned* ub = reinterpret_cast<const unsigned*>(Up) + g * 256 + tid;
      unsigned d[32];
#pragma unroll
      for (int q4 = 0; q4 < 4; ++q4) {
        ld8_dw(ub + (q4 * 8 + 0) * 8192, ub + (q4 * 8 + 1) * 8192,
               ub + (q4 * 8 + 2) * 8192, ub + (q4 * 8 + 3) * 8192,
               ub + (q4 * 8 + 4) * 8192, ub + (q4 * 8 + 5) * 8192,
               ub + (q4 * 8 + 6) * 8192, ub + (q4 * 8 + 7) * 8192,
               d[q4 * 8 + 0], d[q4 * 8 + 1], d[q4 * 8 + 2], d[q4 * 8 + 3],
               d[q4 * 8 + 4], d[q4 * 8 + 5], d[q4 * 8 + 6], d[q4 * 8 + 7]);
      }
      // a2 = ahb + p . Bm (Bmt rows s-contiguous)
      float s0 = ahbp[o2], s1 = ahbp[o2 + 1];
      {
        const bf16* bm0 = Bmt + ((size_t)g * 512 + o2) * 64;
        short8b v0[8], v1[8];
#pragma unroll
        for (int i = 0; i < 8; ++i) {
          v0[i] = ldb8(bm0 + i * 8);
          v1[i] = ldb8(bm0 + 64 + i * 8);
        }
#pragma unroll
        for (int i = 0; i < 8; ++i)
#pragma unroll
          for (int e = 0; e < 8; ++e) {
            const float p = p_lds[i * 8 + e];
            s0 += p * s2f(v0[i][e]);
            s1 += p * s2f(v1[i][e]);
          }
      }
      asm volatile("s_waitcnt vmcnt(0)" ::: "memory");
      float u0 = 0.f, u1 = 0.f;
#pragma unroll
      for (int i = 0; i < 32; ++i) {
        u0 += s2f((short)(d[i] & 0xffffu));
        u1 += s2f((short)(d[i] >> 16));
      }
      const float h0 = tanhf(s0 + u0);
      const float h1 = tanhf(s1 + u1);
      st4_wt(hhW + (size_t)g * 512 + o2, h0, h1);
      const unsigned hp = pack2(h0, h1);
      if (dir == 0) {
        *reinterpret_cast<unsigned*>(P.hcat + (size_t)(g * 64 + t) * 1024 + o2) = hp;
      } else if (t >= 2) {
        *reinterpret_cast<unsigned*>(P.hcat + (size_t)(g * 64 + t - 2) * 1024 + 512 + o2) = hp;
      }
      if (t < 63) {                            // prefetch h_t frags for next Phase A
        const bf16* A0 = hbW + (size_t)lr16 * 512;
        const bf16* A1 = hbW + (size_t)(lr16 + 16) * 512;
#pragma unroll
        for (int ks = 0; ks < 16; ++ks) {
          pA0[ks] = ldb8(A0 + ks * 32 + koff);
          pA1[ks] = ldb8(A1 + ks * 32 + koff);
        }
      }
    }
    gbar(P.flags, ep++, blk, tid);
  }
}

// =======================  host  =======================
extern "C" void kernel_launch(void* const* d_in, const int* in_sizes, int n_in,
                              void* d_out, int out_size, void* d_ws, size_t ws_size,
                              hipStream_t stream) {
  (void)in_sizes; (void)n_in; (void)out_size; (void)ws_size;
  const float* src  = (const float*)d_in[0];
  const int*   trg  = (const int*)d_in[1];
  const float* mask = (const float*)d_in[2];
  const float* emb  = (const float*)d_in[3];
  const float* fWih = (const float*)d_in[4];
  const float* fWhh = (const float*)d_in[5];
  const float* fbih = (const float*)d_in[6];
  const float* fbhh = (const float*)d_in[7];
  const float* bWih = (const float*)d_in[8];
  const float* bWhh = (const float*)d_in[9];
  const float* bbih = (const float*)d_in[10];
  const float* bbhh = (const float*)d_in[11];
  const float* fattW = (const float*)d_in[12];
  const float* fattb = (const float*)d_in[13];
  const float* battW = (const float*)d_in[14];
  const float* battb = (const float*)d_in[15];
  const float* fahW = (const float*)d_in[16];
  const float* fahb = (const float*)d_in[17];
  const float* bahW = (const float*)d_in[18];
  const float* bahb = (const float*)d_in[19];
  const float* fcW  = (const float*)d_in[20];
  const float* fcb  = (const float*)d_in[21];
  const float* feed = (const float*)d_in[22];
  const float* hid  = (const float*)d_in[23];

  char* wsp = (char*)d_ws;
  size_t off = 0;
  auto alloc = [&](size_t bytes) -> void* {
    void* p = wsp + off;
    off += (bytes + 255) & ~(size_t)255;
    return p;
  };
  unsigned* flags = (unsigned*)alloc((size_t)192 * 64 * 4);
  bf16* hcat = (bf16*)alloc((size_t)2048 * 1024 * 2);
  const size_t zero_bytes = off;                 // flags + hcat zeroed per launch
  bf16* xg    = (bf16*)alloc((size_t)2048 * 512 * 2);
  bf16* srcb  = (bf16*)alloc((size_t)2048 * 1024 * 2);
  bf16* fcWb  = (bf16*)alloc((size_t)32000 * 1024 * 2);
  bf16* Wxf   = (bf16*)alloc((size_t)2048 * 512 * 2);
  bf16* Wxb   = (bf16*)alloc((size_t)2048 * 512 * 2);
  bf16* Wrecf = (bf16*)alloc((size_t)2048 * 1024 * 2);
  bf16* Wrecb = (bf16*)alloc((size_t)2048 * 1024 * 2);
  bf16* attWtf = (bf16*)alloc((size_t)512 * 1024 * 2);
  bf16* attWtb = (bf16*)alloc((size_t)512 * 1024 * 2);
  bf16* ahW2f = (bf16*)alloc((size_t)512 * 1024 * 2);
  bf16* ahW2b = (bf16*)alloc((size_t)512 * 1024 * 2);
  bf16* Wh1f  = (bf16*)alloc((size_t)512 * 512 * 2);
  bf16* Wh1b  = (bf16*)alloc((size_t)512 * 512 * 2);
  bf16* Xpf   = (bf16*)alloc((size_t)2048 * 2048 * 2);
  bf16* Xpb   = (bf16*)alloc((size_t)2048 * 2048 * 2);
  bf16* Aff   = (bf16*)alloc((size_t)2048 * 512 * 2);
  bf16* Afb   = (bf16*)alloc((size_t)2048 * 512 * 2);
  bf16* Bmf   = (bf16*)alloc((size_t)2048 * 512 * 2);
  bf16* Bmb   = (bf16*)alloc((size_t)2048 * 512 * 2);
  bf16* Bmtf  = (bf16*)alloc((size_t)2048 * 512 * 2);
  bf16* Bmtb  = (bf16*)alloc((size_t)2048 * 512 * 2);
  bf16* Upf   = (bf16*)alloc((size_t)32 * 32 * 512 * 2);   // [g][b][o]
  bf16* Upb   = (bf16*)alloc((size_t)32 * 32 * 512 * 2);
  float* c0f  = (float*)alloc(2048 * 4);
  float* c0b  = (float*)alloc(2048 * 4);
  bf16* hh0   = (bf16*)alloc((size_t)65 * 32 * 512 * 2);
  bf16* hh1   = (bf16*)alloc((size_t)65 * 32 * 512 * 2);
  bf16* hb0   = (bf16*)alloc((size_t)65 * 32 * 512 * 2);
  bf16* hb1   = (bf16*)alloc((size_t)65 * 32 * 512 * 2);
  float* cst0 = (float*)alloc((size_t)512 * 32 * 4);
  float* cst1 = (float*)alloc((size_t)512 * 32 * 4);

  hipMemsetAsync(d_ws, 0, zero_bytes, stream);

  k_xg<<<4096, 256, 0, stream>>>(emb, trg, xg);
  k_srcb<<<8192, 256, 0, stream>>>(src, srcb);
  k_fcw<<<8192, 256, 0, stream>>>(fcW, fcWb);
  k_wpack<<<2048, 256, 0, stream>>>(fWih, fWhh, bWih, bWhh, fattW, battW, bahW, fahW,
                                    Wxf, Wxb, Wrecf, Wrecb, attWtf, attWtb, ahW2f, ahW2b,
                                    Wh1f, Wh1b);
  k_c0<<<2048, 256, 0, stream>>>(src, fattb, battb, c0f, c0b);
  k_init<<<64, 256, 0, stream>>>(feed, hid, hh0, hh1, hb0, hb1, cst0, cst1);

  // Xp[gc][r] = (x @ Wih_x^T)^T  (gc-major so scan reads are b-coalesced)
  gemm_k<bf16, false><<<dim3(16, 16), 256, 0, stream>>>(Wxf, xg, Xpf, nullptr, 2048, 2048, 512);
  gemm_k<bf16, false><<<dim3(16, 16), 256, 0, stream>>>(Wxb, xg, Xpb, nullptr, 2048, 2048, 512);
  // A[r][j] = src @ attW ;  Bm[r][o] = src @ ahW_ct^T
  gemm_k<bf16, false><<<dim3(4, 16), 256, 0, stream>>>(srcb, attWtf, Aff, nullptr, 2048, 512, 1024);
  gemm_k<bf16, false><<<dim3(4, 16), 256, 0, stream>>>(srcb, attWtb, Afb, nullptr, 2048, 512, 1024);
  gemm_k<bf16, false><<<dim3(4, 16), 256, 0, stream>>>(srcb, ahW2f, Bmf, nullptr, 2048, 512, 1024);
  gemm_k<bf16, false><<<dim3(4, 16), 256, 0, stream>>>(srcb, ahW2b, Bmb, nullptr, 2048, 512, 1024);
  k_bmt<<<4096, 256, 0, stream>>>(Bmf, Bmtf);
  k_bmt<<<4096, 256, 0, stream>>>(Bmb, Bmtb);

  ScanP sp;
  sp.Wrec[0] = Wrecf; sp.Wrec[1] = Wrecb;
  sp.Xp[0] = Xpf;     sp.Xp[1] = Xpb;
  sp.Af[0] = Aff;     sp.Af[1] = Afb;
  sp.Bmt[0] = Bmtf;   sp.Bmt[1] = Bmtb;
  sp.Wh1[0] = Wh1f;   sp.Wh1[1] = Wh1b;
  sp.bih[0] = fbih;   sp.bih[1] = bbih;
  sp.bhh[0] = fbhh;   sp.bhh[1] = bbhh;
  sp.c0[0] = c0f;     sp.c0[1] = c0b;
  sp.ahb[0] = bahb;   sp.ahb[1] = fahb;   // att_hidden weights are swapped in the reference
  sp.mask = mask;
  sp.hh[0] = hh0;     sp.hh[1] = hh1;
  sp.hb[0] = hb0;     sp.hb[1] = hb1;
  sp.Up[0] = Upf;     sp.Up[1] = Upb;
  sp.cst[0] = cst0;   sp.cst[1] = cst1;
  sp.hcat = hcat;     sp.flags = flags;
  scan_k<<<64, 256, 0, stream>>>(sp);

  // logits[b*64+t][v] = hcat @ fcW^T + fcb  (LDS-staged)
  gemm_out<<<4000, 256, 0, stream>>>(hcat, fcWb, (float*)d_out, fcb);
}